// Round 9
// baseline (358.506 us; speedup 1.0000x reference)
//
#include <hip/hip_runtime.h>
#include <hip/hip_fp16.h>
#include <cstdint>
#include <cstddef>

#define NN 1024   // nodes
#define BB 32     // batch

typedef _Float16 f16x8 __attribute__((ext_vector_type(8)));
typedef _Float16 f16x4 __attribute__((ext_vector_type(4)));
typedef float f32x4 __attribute__((ext_vector_type(4)));
typedef float f32x16 __attribute__((ext_vector_type(16)));

__device__ __forceinline__ void load_lds16(const void* g, void* l) {
  __builtin_amdgcn_global_load_lds(
      (const __attribute__((address_space(1))) void*)g,
      (__attribute__((address_space(3))) void*)l, 16, 0, 0);
}

// ---------------------------------------------------------------------------
// K0: build the 10 support matrices (shared by both gconvs), fp16.
// ---------------------------------------------------------------------------
__global__ __launch_bounds__(256) void k_build_amats(
    const float* __restrict__ adj, const float* __restrict__ mask,
    _Float16* __restrict__ A) {
  int q = blockIdx.x * 256 + threadIdx.x;  // 0..262143 quads
  int i = q >> 8;
  int j0 = (q & 255) << 2;
  size_t off = (size_t)i * 1024 + j0;
  float4 a0 = *(const float4*)(adj + off);
  float4 a1 = *(const float4*)(adj + (1u << 20) + off);
  f16x4 r;
  r[0] = a0.x; r[1] = a0.y; r[2] = a0.z; r[3] = a0.w;
  *(f16x4*)(A + off) = r;
  r[0] = a1.x; r[1] = a1.y; r[2] = a1.z; r[3] = a1.w;
  *(f16x4*)(A + (size_t)9 * 1048576 + off) = r;
#pragma unroll
  for (int l = 0; l < 8; ++l) {
    float4 mk = *(const float4*)(mask + (size_t)l * 1048576 + off);
    float4 base = (l < 4) ? a0 : a1;
    r[0] = mk.x * base.x; r[1] = mk.y * base.y;
    r[2] = mk.z * base.z; r[3] = mk.w * base.w;
    *(f16x4*)(A + (size_t)(l + 1) * 1048576 + off) = r;
  }
}

// ---------------------------------------------------------------------------
// K0b: transpose+convert Wout matrices to fp16 hi/lo [O][K]
// ---------------------------------------------------------------------------
__global__ __launch_bounds__(256) void k_prep_wout(
    const float* __restrict__ Wru, const float* __restrict__ Wc,
    _Float16* __restrict__ WThru, _Float16* __restrict__ WTlru,
    _Float16* __restrict__ WThc, _Float16* __restrict__ WTlc) {
  int id = blockIdx.x * 256 + threadIdx.x;
  if (id < 128 * 384) {
    int o = id & 127, k = id >> 7;
    float w = Wru[k * 128 + o];
    _Float16 h = (_Float16)w;
    WThru[o * 384 + k] = h;
    WTlru[o * 384 + k] = (_Float16)(w - (float)h);
  } else {
    int id2 = id - 128 * 384;
    if (id2 < 64 * 192) {
      int o = id2 & 63, k = id2 >> 6;
      float w = Wc[k * 64 + o];
      _Float16 h = (_Float16)w;
      WThc[o * 192 + k] = h;
      WTlc[o * 192 + k] = (_Float16)(w - (float)h);
    }
  }
}

// ---------------------------------------------------------------------------
// K1: build X0P fp16 [(b*1024+j)][96]: f<2 inputs, f-2<64 state, pad 0.
// ---------------------------------------------------------------------------
__global__ __launch_bounds__(256) void k_build_x0p(
    const float* __restrict__ inp, const float* __restrict__ state,
    _Float16* __restrict__ X0P) {
  const int b = blockIdx.x;        // 0..31
  const int j0 = blockIdx.y * 64;  // 0..960
  const int tid = threadIdx.x;
  for (int p = tid; p < 4096; p += 256) {
    int jj = p >> 6, f = p & 63;
    X0P[((size_t)(b * 1024 + j0 + jj)) * 96 + 2 + f] =
        (_Float16)state[(size_t)b * 65536 + (j0 + jj) * 64 + f];
  }
  if (tid < 128) {
    int jj = tid >> 1, f = tid & 1;
    X0P[((size_t)(b * 1024 + j0 + jj)) * 96 + f] =
        (_Float16)inp[(size_t)b * 2048 + (j0 + jj) * 2 + f];
    X0P[((size_t)(b * 1024 + j0 + 32 + jj)) * 96 + f] =
        (_Float16)inp[(size_t)b * 2048 + (j0 + 32 + jj) * 2 + f];
  }
  for (int p = tid; p < 64 * 32; p += 256) {
    int jj = p >> 5, f = 66 + (p & 31);
    if (f < 96)
      X0P[((size_t)(b * 1024 + j0 + jj)) * 96 + f] = (_Float16)0.f;
  }
}

// ---------------------------------------------------------------------------
// K2: proj0 GEMM via MFMA.  XP0[(j,b)][o] = sum_f x[b,j,f] * W[f,o]
// ---------------------------------------------------------------------------
template <int O>
__global__ __launch_bounds__(256, 2) void k_proj0_mfma(
    const _Float16* __restrict__ X0P, const float* __restrict__ W,
    _Float16* __restrict__ XP0, _Float16* __restrict__ XP0T) {
  constexpr int WR = O / 64;      // 2 for O=128, 1 for O=64
  constexpr int WC = 4 / WR;      // 2 or 4
  constexpr int TN = WC * 64;     // 128 or 256
  constexpr int NPT = TN / 64;    // staging chunks per thread (2 or 4)
  __shared__ _Float16 ldsB[2][TN * 32];
  const int tid = threadIdx.x;
  const int c0 = blockIdx.x * TN;  // global col base (b*1024+j), within one b
  const int b = c0 >> 10;
  const int l = tid & 63;
  const int w = tid >> 6;
  const int wr = w / WC, wc = w % WC;

  f16x8 af[4][3];
#pragma unroll
  for (int i = 0; i < 4; ++i) {
    int o = wr * 64 + i * 16 + (l & 15);
#pragma unroll
    for (int ks = 0; ks < 3; ++ks) {
#pragma unroll
      for (int e = 0; e < 8; ++e) {
        int f = ks * 32 + (l >> 4) * 8 + e;
        af[i][ks][e] = (f < 66) ? (_Float16)W[f * O + o] : (_Float16)0.f;
      }
    }
  }

  int tt[NPT], rr[NPT], qq[NPT];
#pragma unroll
  for (int u = 0; u < NPT; ++u) {
    tt[u] = u * 256 + tid;
    rr[u] = tt[u] >> 2;
    qq[u] = (tt[u] & 3) ^ (rr[u] & 3);
  }

  const int ps = ((l >> 4) ^ (l & 3)) * 8;
  int offB[4];
#pragma unroll
  for (int j = 0; j < 4; ++j)
    offB[j] = (wc * 64 + j * 16 + (l & 15)) * 32 + ps;

  f32x4 acc[4][4];
#pragma unroll
  for (int i = 0; i < 4; ++i)
#pragma unroll
    for (int j = 0; j < 4; ++j) acc[i][j] = (f32x4){0.f, 0.f, 0.f, 0.f};

#pragma unroll
  for (int u = 0; u < NPT; ++u)
    load_lds16(X0P + (size_t)(c0 + rr[u]) * 96 + qq[u] * 8,
               &ldsB[0][0] + tt[u] * 8);

  int buf = 0;
  for (int kt = 0; kt < 3; ++kt) {
    __syncthreads();
    if (kt + 1 < 3) {
#pragma unroll
      for (int u = 0; u < NPT; ++u)
        load_lds16(X0P + (size_t)(c0 + rr[u]) * 96 + (kt + 1) * 32 + qq[u] * 8,
                   &ldsB[buf ^ 1][0] + tt[u] * 8);
    }
    f16x8 bf[4];
#pragma unroll
    for (int j = 0; j < 4; ++j) bf[j] = *(const f16x8*)(&ldsB[buf][offB[j]]);
#pragma unroll
    for (int i = 0; i < 4; ++i)
#pragma unroll
      for (int j = 0; j < 4; ++j)
        acc[i][j] = __builtin_amdgcn_mfma_f32_16x16x32_f16(af[i][kt], bf[j],
                                                           acc[i][j], 0, 0, 0);
    buf ^= 1;
  }

#pragma unroll
  for (int i = 0; i < 4; ++i) {
    int ob = wr * 64 + i * 16 + (l >> 4) * 4;  // 4 consecutive o
#pragma unroll
    for (int j = 0; j < 4; ++j) {
      int jn = (c0 & 1023) + wc * 64 + j * 16 + (l & 15);
      f16x4 hv;
#pragma unroll
      for (int r = 0; r < 4; ++r) {
        hv[r] = (_Float16)acc[i][j][r];
        XP0T[((size_t)b * O + ob + r) * 1024 + jn] = hv[r];
      }
      *(f16x4*)(XP0 + ((size_t)jn * 32 + b) * O + ob) = hv;
    }
  }
}

// ---------------------------------------------------------------------------
// K3: supports GEMM, counted-vmcnt ring-3 schedule (T3+T4+T5).
// XPD[(m*1024+i)][c] = sum_j A_m[i][j] * XP0T[c][j],  c = b*O+o, CN=32*O.
// BM=256 x BN=128 tile, BK=32, 4 waves (2M x 2N), each 128x64 via 4x2
// 32x32x16 frags (layout verified round 7).  LDS ring of 3 K-tile slots
// (72 KB, 2 blocks/CU).  Compute tile t from slot t%3 while staging t+2
// into (t+2)%3; one s_barrier per tile; steady-state s_waitcnt vmcnt(6).
// Swizzle: phys k-chunk = logical ^ ((row>>1)&3) (conflict-free for the
// 32-row fragment read; round-7's ^(row&3) aliased quads -> 3x conflicts).
// ---------------------------------------------------------------------------
template <int CN>
__global__ __launch_bounds__(256, 2) void k_supports3_mfma(
    const _Float16* __restrict__ A, const _Float16* __restrict__ BT,
    _Float16* __restrict__ XPD) {
  __shared__ _Float16 ldsA[3][8192];  // [slot][256 rows][32 k]
  __shared__ _Float16 ldsB[3][4096];  // [slot][128 rows][32 k]
  const int tid = threadIdx.x;
  const int bn = blockIdx.x;  // CN/128
  const int bm = blockIdx.y;  // 0..39
  const int l = tid & 63;
  const int w = tid >> 6;
  const int wm = w >> 1, wn = w & 1;

  // staging: thread covers phys chunks tid + k*256; source k-chunk lg
  const int r0 = tid >> 2;                     // 0..63
  const int lg = (tid & 3) ^ ((r0 >> 1) & 3);  // invariant under row+64
  const _Float16* gA = A + ((size_t)(bm * 256 + r0)) * 1024 + lg * 8;
  const _Float16* gB = BT + ((size_t)(bn * 128 + r0)) * 1024 + lg * 8;
  _Float16* const dA0 = &ldsA[0][0] + tid * 8;
  _Float16* const dB0 = &ldsB[0][0] + tid * 8;

#define STAGE_A3(t, s)                                      \
  {                                                         \
    const _Float16* g_ = gA + (t) * 32;                     \
    _Float16* d_ = dA0 + (s) * 8192;                        \
    load_lds16(g_, d_);                                     \
    load_lds16(g_ + 64 * 1024, d_ + 2048);                  \
    load_lds16(g_ + 128 * 1024, d_ + 4096);                 \
    load_lds16(g_ + 192 * 1024, d_ + 6144);                 \
  }
#define STAGE_B3(t, s)                                      \
  {                                                         \
    const _Float16* g_ = gB + (t) * 32;                     \
    _Float16* d_ = dB0 + (s) * 4096;                        \
    load_lds16(g_, d_);                                     \
    load_lds16(g_ + 64 * 1024, d_ + 2048);                  \
  }

  // fragment read offsets (halfs): row*32 + phys_chunk*8
  const int lr = l & 31, lh = l >> 5;
  const int sx = (lr >> 1) & 3;
  int pk[2];
  pk[0] = lh ^ sx;
  pk[1] = (2 + lh) ^ sx;
  int offA_[4][2], offB_[2][2];
#pragma unroll
  for (int fi = 0; fi < 4; ++fi)
#pragma unroll
    for (int ks = 0; ks < 2; ++ks)
      offA_[fi][ks] = (wm * 128 + fi * 32 + lr) * 32 + pk[ks] * 8;
#pragma unroll
  for (int fj = 0; fj < 2; ++fj)
#pragma unroll
    for (int ks = 0; ks < 2; ++ks)
      offB_[fj][ks] = (wn * 64 + fj * 32 + lr) * 32 + pk[ks] * 8;

  f32x16 acc[4][2];
#pragma unroll
  for (int i = 0; i < 4; ++i)
#pragma unroll
    for (int j = 0; j < 2; ++j)
#pragma unroll
      for (int e = 0; e < 16; ++e) acc[i][j][e] = 0.f;

  // prologue: stage tiles 0,1 (12 loads/thread)
  STAGE_A3(0, 0); STAGE_B3(0, 0);
  STAGE_A3(1, 1); STAGE_B3(1, 1);

  int slot = 0;
  for (int t = 0; t < 32; ++t) {
    if (t < 31)
      asm volatile("s_waitcnt vmcnt(6)" ::: "memory");
    else
      asm volatile("s_waitcnt vmcnt(0)" ::: "memory");
    __builtin_amdgcn_sched_barrier(0);
    __builtin_amdgcn_s_barrier();
    __builtin_amdgcn_sched_barrier(0);
    const int s2 = (slot >= 1) ? slot - 1 : slot + 2;  // (t+2)%3
    // ---- phase 0: stage A(t+2); read B-frags + A rows 0-1; MFMA
    if (t + 2 < 32) STAGE_A3(t + 2, s2);
    f16x8 bf[2][2], af[2][2];
#pragma unroll
    for (int ks = 0; ks < 2; ++ks) {
      bf[0][ks] = *(const f16x8*)(&ldsB[slot][offB_[0][ks]]);
      bf[1][ks] = *(const f16x8*)(&ldsB[slot][offB_[1][ks]]);
      af[0][ks] = *(const f16x8*)(&ldsA[slot][offA_[0][ks]]);
      af[1][ks] = *(const f16x8*)(&ldsA[slot][offA_[1][ks]]);
    }
    asm volatile("s_waitcnt lgkmcnt(0)" ::: "memory");
    __builtin_amdgcn_sched_barrier(0);
    __builtin_amdgcn_s_setprio(1);
#pragma unroll
    for (int fi = 0; fi < 2; ++fi)
#pragma unroll
      for (int fj = 0; fj < 2; ++fj)
#pragma unroll
        for (int ks = 0; ks < 2; ++ks)
          acc[fi][fj] = __builtin_amdgcn_mfma_f32_32x32x16_f16(
              af[fi][ks], bf[fj][ks], acc[fi][fj], 0, 0, 0);
    __builtin_amdgcn_s_setprio(0);
    // ---- phase 1: stage B(t+2); read A rows 2-3; MFMA
    if (t + 2 < 32) STAGE_B3(t + 2, s2);
    f16x8 ag[2][2];
#pragma unroll
    for (int ks = 0; ks < 2; ++ks) {
      ag[0][ks] = *(const f16x8*)(&ldsA[slot][offA_[2][ks]]);
      ag[1][ks] = *(const f16x8*)(&ldsA[slot][offA_[3][ks]]);
    }
    asm volatile("s_waitcnt lgkmcnt(0)" ::: "memory");
    __builtin_amdgcn_sched_barrier(0);
    __builtin_amdgcn_s_setprio(1);
#pragma unroll
    for (int fi = 0; fi < 2; ++fi)
#pragma unroll
      for (int fj = 0; fj < 2; ++fj)
#pragma unroll
        for (int ks = 0; ks < 2; ++ks)
          acc[fi + 2][fj] = __builtin_amdgcn_mfma_f32_32x32x16_f16(
              ag[fi][ks], bf[fj][ks], acc[fi + 2][fj], 0, 0, 0);
    __builtin_amdgcn_s_setprio(0);
    slot = (slot == 2) ? 0 : slot + 1;
  }

  // epilogue: C/D layout col = lane&31, row = (e&3) + 8*(e>>2) + 4*(lane>>5)
#pragma unroll
  for (int fi = 0; fi < 4; ++fi) {
    int Rb = bm * 256 + wm * 128 + fi * 32 + 4 * lh;
#pragma unroll
    for (int fj = 0; fj < 2; ++fj) {
      int col = bn * 128 + wn * 64 + fj * 32 + lr;
#pragma unroll
      for (int e = 0; e < 16; ++e) {
        int R = Rb + (e & 3) + 8 * (e >> 2);
        XPD[(size_t)R * CN + col] = (_Float16)acc[fi][fj][e];
      }
    }
  }
#undef STAGE_A3
#undef STAGE_B3
}

// ---------------------------------------------------------------------------
// K4: attention via MFMA (reads XPD rows [(s'*1024+n)][CN], s'=g*5+si).
// Writes xi/xs as fp16 hi+lo into CAT2h/CAT2l [(n*32+b)][2*O].
// ---------------------------------------------------------------------------
template <int O>
__global__ __launch_bounds__(256) void k_attend_mfma(
    const __half* __restrict__ XPD, const float* __restrict__ Watt,
    const float* __restrict__ Watt1, _Float16* __restrict__ CAT2h,
    _Float16* __restrict__ CAT2l) {
  constexpr int MTW = O / 64;       // q-tiles per wave (2 or 1)
  constexpr int KS = O / 32;        // k-steps (4 or 2)
  constexpr int SLOTS = O / 8;      // 16B slots per row (16 or 8)
  constexpr int SWZ = SLOTS - 1;
  constexpr int OH = O / 2;         // u32 per (b) slice
  const int n = blockIdx.x;
  const int tid = threadIdx.x;
  const int l = tid & 63;
  const int w = tid >> 6;

  __shared__ _Float16 xpL[160 * O];
  __shared__ float sPartL[4][160];
  __shared__ float aL[32][5];

  const int qbase = w * (O / 4);
  f16x8 afr[MTW][KS];
#pragma unroll
  for (int mt = 0; mt < MTW; ++mt) {
    const int q = qbase + mt * 16 + (l & 15);
#pragma unroll
    for (int ks = 0; ks < KS; ++ks) {
#pragma unroll
      for (int e = 0; e < 8; ++e) {
        int o = ks * 32 + (l >> 4) * 8 + e;
        afr[mt][ks][e] = (_Float16)Watt[((size_t)n * O + o) * O + q];
      }
    }
  }
  float wt1[MTW][4];
#pragma unroll
  for (int mt = 0; mt < MTW; ++mt)
#pragma unroll
    for (int r = 0; r < 4; ++r)
      wt1[mt][r] = Watt1[(size_t)n * O + qbase + mt * 16 + (l >> 4) * 4 + r];

  for (int g = 0; g < 2; ++g) {
    if (g) __syncthreads();
    {
      const uint32_t* xsrc = reinterpret_cast<const uint32_t*>(XPD);
      uint32_t* xdst = reinterpret_cast<uint32_t*>(xpL);
      for (int p = tid; p < 160 * OH; p += 256) {
        int row = p / OH;
        int oh = p - row * OH;
        int slot = oh >> 2;
        int phys = slot ^ (row & SWZ);
        int si = row >> 5, b = row & 31;
        size_t gi = ((size_t)(g * 5 + si) * 1024 + n) * (size_t)(16 * O) +
                    b * OH + oh;
        xdst[row * OH + phys * 4 + (oh & 3)] = xsrc[gi];
      }
    }
    __syncthreads();

    for (int nt = 0; nt < 10; ++nt) {
      f32x4 acc[MTW];
#pragma unroll
      for (int mt = 0; mt < MTW; ++mt) acc[mt] = (f32x4){0.f, 0.f, 0.f, 0.f};
      const int row = nt * 16 + (l & 15);
#pragma unroll
      for (int ks = 0; ks < KS; ++ks) {
        int phys = (ks * 4 + (l >> 4)) ^ (row & SWZ);
        f16x8 bf = *(const f16x8*)(&xpL[row * O + phys * 8]);
#pragma unroll
        for (int mt = 0; mt < MTW; ++mt)
          acc[mt] = __builtin_amdgcn_mfma_f32_16x16x32_f16(afr[mt][ks], bf,
                                                           acc[mt], 0, 0, 0);
      }
      float sp = 0.f;
#pragma unroll
      for (int mt = 0; mt < MTW; ++mt)
#pragma unroll
        for (int r = 0; r < 4; ++r)
          sp += fmaxf(acc[mt][r], 0.f) * wt1[mt][r];
      sp += __shfl_xor(sp, 16);
      sp += __shfl_xor(sp, 32);
      if (l < 16) sPartL[w][nt * 16 + l] = sp;
    }
    __syncthreads();

    if (tid < 32) {
      const int b = tid;
      float sv[5];
#pragma unroll
      for (int k = 0; k < 5; ++k) {
        int row = k * 32 + b;
        sv[k] = sPartL[0][row] + sPartL[1][row] + sPartL[2][row] +
                sPartL[3][row];
      }
      float mx = sv[0];
#pragma unroll
      for (int k = 1; k < 5; ++k) mx = fmaxf(mx, sv[k]);
      float e[5], sum = 0.f;
#pragma unroll
      for (int k = 0; k < 5; ++k) {
        e[k] = expf(sv[k] - mx);
        sum += e[k];
      }
      float inv = 1.f / sum;
#pragma unroll
      for (int k = 0; k < 5; ++k) aL[b][k] = e[k] * inv;
    }
    __syncthreads();

    for (int it = 0; it < SLOTS * 32 / 256; ++it) {
      int idx = it * 256 + tid;
      int b = idx & 31;
      int sc = idx >> 5;
      float o8[8] = {0.f, 0.f, 0.f, 0.f, 0.f, 0.f, 0.f, 0.f};
#pragma unroll
      for (int si = 0; si < 5; ++si) {
        int row = si * 32 + b;
        int phys = sc ^ (row & SWZ);
        f16x8 xv = *(const f16x8*)(&xpL[row * O + phys * 8]);
        float a = aL[b][si];
#pragma unroll
        for (int j = 0; j < 8; ++j) o8[j] += a * (float)xv[j];
      }
      f16x8 hv, lv;
#pragma unroll
      for (int j = 0; j < 8; ++j) {
        hv[j] = (_Float16)o8[j];
        lv[j] = (_Float16)(o8[j] - (float)hv[j]);
      }
      size_t doff = ((size_t)n * 32 + b) * (2 * O) + g * O + sc * 8;
      *reinterpret_cast<f16x8*>(CAT2h + doff) = hv;
      *reinterpret_cast<f16x8*>(CAT2l + doff) = lv;
    }
  }
}

// ---------------------------------------------------------------------------
// K5: ru Wout GEMM via split-fp16 MFMA + fused sigmoid.
// ---------------------------------------------------------------------------
__global__ __launch_bounds__(256, 2) void k_wout_ru_mfma(
    const _Float16* __restrict__ CAT2h, const _Float16* __restrict__ CAT2l,
    const _Float16* __restrict__ XP0, const _Float16* __restrict__ WTh,
    const _Float16* __restrict__ WTl, const float* __restrict__ bias,
    const float* __restrict__ hx, float* __restrict__ RHX,
    float* __restrict__ UBUF) {
  constexpr int KTOT = 384, KC = 8, KT = 12;
  __shared__ _Float16 ldsAh[2][4096];
  __shared__ _Float16 ldsAl[2][4096];
  __shared__ _Float16 ldsBh[2][4096];
  __shared__ _Float16 ldsBl[2][4096];
  const int tid = threadIdx.x;
  const int blk = blockIdx.x;
  const int l = tid & 63;
  const int w = tid >> 6;
  const int wr = w >> 1, wc = w & 1;

  const int t0 = tid, t1 = 256 + tid;
  const int r0 = t0 >> 2, q0 = (t0 & 3) ^ (r0 & 3);
  const int r1 = t1 >> 2, q1 = (t1 & 3) ^ (r1 & 3);
  const size_t R0 = (size_t)blk * 128 + r0, R1 = (size_t)blk * 128 + r1;
  const _Float16* pA0ch = CAT2h + R0 * 256 + q0 * 8;
  const _Float16* pA1ch = CAT2h + R1 * 256 + q1 * 8;
  const _Float16* pA0cl = CAT2l + R0 * 256 + q0 * 8;
  const _Float16* pA1cl = CAT2l + R1 * 256 + q1 * 8;
  const _Float16* pA0x = XP0 + R0 * 128 + q0 * 8;
  const _Float16* pA1x = XP0 + R1 * 128 + q1 * 8;
  const _Float16* pB0h = WTh + (size_t)r0 * KTOT + q0 * 8;
  const _Float16* pB1h = WTh + (size_t)r1 * KTOT + q1 * 8;
  const _Float16* pB0l = WTl + (size_t)r0 * KTOT + q0 * 8;
  const _Float16* pB1l = WTl + (size_t)r1 * KTOT + q1 * 8;

  const int ps = ((l >> 4) ^ (l & 3)) * 8;
  int offA[4], offB[4];
#pragma unroll
  for (int i = 0; i < 4; ++i) {
    offA[i] = (wr * 64 + i * 16 + (l & 15)) * 32 + ps;
    offB[i] = (wc * 64 + i * 16 + (l & 15)) * 32 + ps;
  }

  f32x4 acc[4][4];
#pragma unroll
  for (int i = 0; i < 4; ++i)
#pragma unroll
    for (int j = 0; j < 4; ++j) acc[i][j] = (f32x4){0.f, 0.f, 0.f, 0.f};

  load_lds16(pA0ch, &ldsAh[0][0] + t0 * 8);
  load_lds16(pA1ch, &ldsAh[0][0] + t1 * 8);
  load_lds16(pA0cl, &ldsAl[0][0] + t0 * 8);
  load_lds16(pA1cl, &ldsAl[0][0] + t1 * 8);
  load_lds16(pB0h, &ldsBh[0][0] + t0 * 8);
  load_lds16(pB1h, &ldsBh[0][0] + t1 * 8);
  load_lds16(pB0l, &ldsBl[0][0] + t0 * 8);
  load_lds16(pB1l, &ldsBl[0][0] + t1 * 8);

  int buf = 0;
  for (int kt = 0; kt < KT; ++kt) {
    __syncthreads();
    if (kt + 1 < KT) {
      int k1 = kt + 1;
      const _Float16* a0 =
          (k1 < KC) ? pA0ch + k1 * 32 : pA0x + (k1 - KC) * 32;
      const _Float16* a1 =
          (k1 < KC) ? pA1ch + k1 * 32 : pA1x + (k1 - KC) * 32;
      load_lds16(a0, &ldsAh[buf ^ 1][0] + t0 * 8);
      load_lds16(a1, &ldsAh[buf ^ 1][0] + t1 * 8);
      if (k1 < KC) {
        load_lds16(pA0cl + k1 * 32, &ldsAl[buf ^ 1][0] + t0 * 8);
        load_lds16(pA1cl + k1 * 32, &ldsAl[buf ^ 1][0] + t1 * 8);
      }
      load_lds16(pB0h + k1 * 32, &ldsBh[buf ^ 1][0] + t0 * 8);
      load_lds16(pB1h + k1 * 32, &ldsBh[buf ^ 1][0] + t1 * 8);
      load_lds16(pB0l + k1 * 32, &ldsBl[buf ^ 1][0] + t0 * 8);
      load_lds16(pB1l + k1 * 32, &ldsBl[buf ^ 1][0] + t1 * 8);
    }
    f16x8 ah[4], bh[4], bl[4];
#pragma unroll
    for (int i = 0; i < 4; ++i) ah[i] = *(const f16x8*)(&ldsAh[buf][offA[i]]);
#pragma unroll
    for (int i = 0; i < 4; ++i) bh[i] = *(const f16x8*)(&ldsBh[buf][offB[i]]);
#pragma unroll
    for (int i = 0; i < 4; ++i) bl[i] = *(const f16x8*)(&ldsBl[buf][offB[i]]);
#pragma unroll
    for (int i = 0; i < 4; ++i)
#pragma unroll
      for (int j = 0; j < 4; ++j) {
        acc[i][j] = __builtin_amdgcn_mfma_f32_16x16x32_f16(ah[i], bh[j],
                                                           acc[i][j], 0, 0, 0);
        acc[i][j] = __builtin_amdgcn_mfma_f32_16x16x32_f16(ah[i], bl[j],
                                                           acc[i][j], 0, 0, 0);
      }
    if (kt < KC) {
      f16x8 al[4];
#pragma unroll
      for (int i = 0; i < 4; ++i)
        al[i] = *(const f16x8*)(&ldsAl[buf][offA[i]]);
#pragma unroll
      for (int i = 0; i < 4; ++i)
#pragma unroll
        for (int j = 0; j < 4; ++j)
          acc[i][j] = __builtin_amdgcn_mfma_f32_16x16x32_f16(al[i], bh[j],
                                                             acc[i][j], 0, 0, 0);
    }
    buf ^= 1;
  }

#pragma unroll
  for (int i = 0; i < 4; ++i) {
    int R = blk * 128 + wr * 64 + i * 16 + (l >> 4) * 4;
#pragma unroll
    for (int j = 0; j < 4; ++j) {
      int o = wc * 64 + j * 16 + (l & 15);
      float bv = bias[o];
#pragma unroll
      for (int rr = 0; rr < 4; ++rr) {
        int Rr = R + rr;
        int n = Rr >> 5, b = Rr & 31;
        size_t base = ((size_t)b * NN + n) * 64;
        float val = 1.f / (1.f + expf(-(acc[i][j][rr] + bv)));
        if (o < 64)
          RHX[base + o] = val * hx[base + o];
        else
          UBUF[base + (o - 64)] = val;
      }
    }
  }
}

// ---------------------------------------------------------------------------
// K6: candidate Wout GEMM (plain fp16 MFMA; terminal op) + tanh + gate -> out.
// ---------------------------------------------------------------------------
__global__ __launch_bounds__(256, 2) void k_wout_c_mfma(
    const _Float16* __restrict__ CAT2h, const _Float16* __restrict__ XP0,
    const _Float16* __restrict__ WTh, const float* __restrict__ bias,
    const float* __restrict__ UBUF, const float* __restrict__ hx,
    float* __restrict__ out) {
  constexpr int KTOT = 192, KC = 4, KT = 6;
  __shared__ _Float16 ldsAh[2][4096];
  __shared__ _Float16 ldsBh[2][2048];
  const int tid = threadIdx.x;
  const int blk = blockIdx.x;
  const int l = tid & 63;
  const int w = tid >> 6;

  const int t0 = tid, t1 = 256 + tid;
  const int r0 = t0 >> 2, q0 = (t0 & 3) ^ (r0 & 3);
  const int r1 = t1 >> 2, q1 = (t1 & 3) ^ (r1 & 3);
  const size_t R0 = (size_t)blk * 128 + r0, R1 = (size_t)blk * 128 + r1;
  const _Float16* pA0ch = CAT2h + R0 * 128 + q0 * 8;
  const _Float16* pA1ch = CAT2h + R1 * 128 + q1 * 8;
  const _Float16* pA0x = XP0 + R0 * 64 + q0 * 8;
  const _Float16* pA1x = XP0 + R1 * 64 + q1 * 8;
  const int rb = tid >> 2, qb = (tid & 3) ^ (rb & 3);
  const _Float16* pBh = WTh + (size_t)rb * KTOT + qb * 8;

  const int ps = ((l >> 4) ^ (l & 3)) * 8;
  int offA[2], offB[4];
#pragma unroll
  for (int i = 0; i < 2; ++i)
    offA[i] = (w * 32 + i * 16 + (l & 15)) * 32 + ps;
#pragma unroll
  for (int j = 0; j < 4; ++j) offB[j] = (j * 16 + (l & 15)) * 32 + ps;

  f32x4 acc[2][4];
#pragma unroll
  for (int i = 0; i < 2; ++i)
#pragma unroll
    for (int j = 0; j < 4; ++j) acc[i][j] = (f32x4){0.f, 0.f, 0.f, 0.f};

  load_lds16(pA0ch, &ldsAh[0][0] + t0 * 8);
  load_lds16(pA1ch, &ldsAh[0][0] + t1 * 8);
  load_lds16(pBh, &ldsBh[0][0] + tid * 8);

  int buf = 0;
  for (int kt = 0; kt < KT; ++kt) {
    __syncthreads();
    if (kt + 1 < KT) {
      int k1 = kt + 1;
      const _Float16* a0 =
          (k1 < KC) ? pA0ch + k1 * 32 : pA0x + (k1 - KC) * 32;
      const _Float16* a1 =
          (k1 < KC) ? pA1ch + k1 * 32 : pA1x + (k1 - KC) * 32;
      load_lds16(a0, &ldsAh[buf ^ 1][0] + t0 * 8);
      load_lds16(a1, &ldsAh[buf ^ 1][0] + t1 * 8);
      load_lds16(pBh + k1 * 32, &ldsBh[buf ^ 1][0] + tid * 8);
    }
    f16x8 ah[2], bh[4];
#pragma unroll
    for (int i = 0; i < 2; ++i) ah[i] = *(const f16x8*)(&ldsAh[buf][offA[i]]);
#pragma unroll
    for (int j = 0; j < 4; ++j) bh[j] = *(const f16x8*)(&ldsBh[buf][offB[j]]);
#pragma unroll
    for (int i = 0; i < 2; ++i)
#pragma unroll
      for (int j = 0; j < 4; ++j)
        acc[i][j] = __builtin_amdgcn_mfma_f32_16x16x32_f16(ah[i], bh[j],
                                                           acc[i][j], 0, 0, 0);
    buf ^= 1;
  }

#pragma unroll
  for (int i = 0; i < 2; ++i) {
    int R = blk * 128 + w * 32 + i * 16 + (l >> 4) * 4;
#pragma unroll
    for (int j = 0; j < 4; ++j) {
      int o = j * 16 + (l & 15);
      float bv = bias[o];
#pragma unroll
      for (int rr = 0; rr < 4; ++rr) {
        int Rr = R + rr;
        int n = Rr >> 5, b = Rr & 31;
        size_t idx = ((size_t)b * NN + n) * 64 + o;
        float cval = tanhf(acc[i][j][rr] + bv);
        float u = UBUF[idx];
        out[idx] = u * hx[idx] + (1.f - u) * cval;
      }
    }
  }
}

// ---------------------------------------------------------------------------
extern "C" void kernel_launch(void* const* d_in, const int* in_sizes, int n_in,
                              void* d_out, int out_size, void* d_ws,
                              size_t ws_size, hipStream_t stream) {
  const float* inputs   = (const float*)d_in[0];
  const float* hx       = (const float*)d_in[1];
  const float* adj      = (const float*)d_in[2];
  const float* mask     = (const float*)d_in[3];
  const float* W_ru     = (const float*)d_in[4];
  const float* Watt_ru  = (const float*)d_in[5];
  const float* Watt1_ru = (const float*)d_in[6];
  const float* Wout_ru  = (const float*)d_in[7];
  const float* b_ru     = (const float*)d_in[8];
  const float* W_c      = (const float*)d_in[9];
  const float* Watt_c   = (const float*)d_in[10];
  const float* Watt1_c  = (const float*)d_in[11];
  const float* Wout_c   = (const float*)d_in[12];
  const float* b_c      = (const float*)d_in[13];

  // workspace arena (~178.5 MB), same as round 6/8
  char* ws = (char*)d_ws;
  _Float16*  X0P   = (_Float16*)(ws);
  _Float16*  XPD   = (_Float16*)(ws + 6291456);
  _Float16*  XP0   = (_Float16*)(ws + 90177536);
  _Float16*  XP0T  = (_Float16*)(ws + 98566144);
  _Float16*  CAT2h = (_Float16*)(ws + 106954752);
  _Float16*  CAT2l = (_Float16*)(ws + 123731968);
  float*     RHX   = (float*)(ws + 140509184);
  float*     UBUF  = (float*)(ws + 148897792);
  _Float16*  A_all = (_Float16*)(ws + 157286400);
  _Float16*  WThru = (_Float16*)(ws + 178257920);
  _Float16*  WTlru = (_Float16*)(ws + 178356224);
  _Float16*  WThc  = (_Float16*)(ws + 178454528);
  _Float16*  WTlc  = (_Float16*)(ws + 178479104);
  float*     out   = (float*)d_out;

  k_build_amats<<<1024, 256, 0, stream>>>(adj, mask, A_all);
  k_prep_wout<<<240, 256, 0, stream>>>(Wout_ru, Wout_c, WThru, WTlru, WThc,
                                       WTlc);

  // ---- gate gconv (O = 2U = 128) ----
  k_build_x0p<<<dim3(32, 16), 256, 0, stream>>>(inputs, hx, X0P);
  k_proj0_mfma<128><<<256, 256, 0, stream>>>(X0P, W_ru, XP0, XP0T);
  k_supports3_mfma<4096><<<dim3(32, 40), 256, 0, stream>>>(A_all, XP0T, XPD);
  k_attend_mfma<128><<<1024, 256, 0, stream>>>((const __half*)XPD, Watt_ru,
                                               Watt1_ru, CAT2h, CAT2l);
  k_wout_ru_mfma<<<256, 256, 0, stream>>>(CAT2h, CAT2l, XP0, WThru, WTlru,
                                          b_ru, hx, RHX, UBUF);
  // ---- candidate gconv (O = U = 64), state = r*hx ----
  k_build_x0p<<<dim3(32, 16), 256, 0, stream>>>(inputs, RHX, X0P);
  k_proj0_mfma<64><<<128, 256, 0, stream>>>(X0P, W_c, XP0, XP0T);
  k_supports3_mfma<2048><<<dim3(16, 40), 256, 0, stream>>>(A_all, XP0T, XPD);
  k_attend_mfma<64><<<1024, 256, 0, stream>>>((const __half*)XPD, Watt_c,
                                              Watt1_c, CAT2h, CAT2l);
  k_wout_c_mfma<<<256, 256, 0, stream>>>(CAT2h, XP0, WThc, b_c,
                                         UBUF, hx, out);
}

// Round 10
// 340.009 us; speedup vs baseline: 1.0544x; 1.0544x over previous
//
#include <hip/hip_runtime.h>
#include <hip/hip_fp16.h>
#include <cstdint>
#include <cstddef>

#define NN 1024   // nodes
#define BB 32     // batch

typedef _Float16 f16x8 __attribute__((ext_vector_type(8)));
typedef _Float16 f16x4 __attribute__((ext_vector_type(4)));
typedef float f32x4 __attribute__((ext_vector_type(4)));

__device__ __forceinline__ void load_lds16(const void* g, void* l) {
  __builtin_amdgcn_global_load_lds(
      (const __attribute__((address_space(1))) void*)g,
      (__attribute__((address_space(3))) void*)l, 16, 0, 0);
}

// ---------------------------------------------------------------------------
// K0: build the 10 support matrices (shared by both gconvs), fp16.
// ---------------------------------------------------------------------------
__global__ __launch_bounds__(256) void k_build_amats(
    const float* __restrict__ adj, const float* __restrict__ mask,
    _Float16* __restrict__ A) {
  int q = blockIdx.x * 256 + threadIdx.x;  // 0..262143 quads
  int i = q >> 8;
  int j0 = (q & 255) << 2;
  size_t off = (size_t)i * 1024 + j0;
  float4 a0 = *(const float4*)(adj + off);
  float4 a1 = *(const float4*)(adj + (1u << 20) + off);
  f16x4 r;
  r[0] = a0.x; r[1] = a0.y; r[2] = a0.z; r[3] = a0.w;
  *(f16x4*)(A + off) = r;
  r[0] = a1.x; r[1] = a1.y; r[2] = a1.z; r[3] = a1.w;
  *(f16x4*)(A + (size_t)9 * 1048576 + off) = r;
#pragma unroll
  for (int l = 0; l < 8; ++l) {
    float4 mk = *(const float4*)(mask + (size_t)l * 1048576 + off);
    float4 base = (l < 4) ? a0 : a1;
    r[0] = mk.x * base.x; r[1] = mk.y * base.y;
    r[2] = mk.z * base.z; r[3] = mk.w * base.w;
    *(f16x4*)(A + (size_t)(l + 1) * 1048576 + off) = r;
  }
}

// ---------------------------------------------------------------------------
// K0b: transpose+convert Wout matrices to fp16 hi/lo [O][K]
// ---------------------------------------------------------------------------
__global__ __launch_bounds__(256) void k_prep_wout(
    const float* __restrict__ Wru, const float* __restrict__ Wc,
    _Float16* __restrict__ WThru, _Float16* __restrict__ WTlru,
    _Float16* __restrict__ WThc, _Float16* __restrict__ WTlc) {
  int id = blockIdx.x * 256 + threadIdx.x;
  if (id < 128 * 384) {
    int o = id & 127, k = id >> 7;
    float w = Wru[k * 128 + o];
    _Float16 h = (_Float16)w;
    WThru[o * 384 + k] = h;
    WTlru[o * 384 + k] = (_Float16)(w - (float)h);
  } else {
    int id2 = id - 128 * 384;
    if (id2 < 64 * 192) {
      int o = id2 & 63, k = id2 >> 6;
      float w = Wc[k * 64 + o];
      _Float16 h = (_Float16)w;
      WThc[o * 192 + k] = h;
      WTlc[o * 192 + k] = (_Float16)(w - (float)h);
    }
  }
}

// ---------------------------------------------------------------------------
// K1: build X0P fp16 [(b*1024+j)][96]: f<2 inputs, f-2<64 state, pad 0.
// ---------------------------------------------------------------------------
__global__ __launch_bounds__(256) void k_build_x0p(
    const float* __restrict__ inp, const float* __restrict__ state,
    _Float16* __restrict__ X0P) {
  const int b = blockIdx.x;        // 0..31
  const int j0 = blockIdx.y * 64;  // 0..960
  const int tid = threadIdx.x;
  for (int p = tid; p < 4096; p += 256) {
    int jj = p >> 6, f = p & 63;
    X0P[((size_t)(b * 1024 + j0 + jj)) * 96 + 2 + f] =
        (_Float16)state[(size_t)b * 65536 + (j0 + jj) * 64 + f];
  }
  if (tid < 128) {
    int jj = tid >> 1, f = tid & 1;
    X0P[((size_t)(b * 1024 + j0 + jj)) * 96 + f] =
        (_Float16)inp[(size_t)b * 2048 + (j0 + jj) * 2 + f];
    X0P[((size_t)(b * 1024 + j0 + 32 + jj)) * 96 + f] =
        (_Float16)inp[(size_t)b * 2048 + (j0 + 32 + jj) * 2 + f];
  }
  for (int p = tid; p < 64 * 32; p += 256) {
    int jj = p >> 5, f = 66 + (p & 31);
    if (f < 96)
      X0P[((size_t)(b * 1024 + j0 + jj)) * 96 + f] = (_Float16)0.f;
  }
}

// ---------------------------------------------------------------------------
// K2: proj0 GEMM via MFMA.  XP0[(j,b)][o] = sum_f x[b,j,f] * W[f,o]
// ---------------------------------------------------------------------------
template <int O>
__global__ __launch_bounds__(256, 2) void k_proj0_mfma(
    const _Float16* __restrict__ X0P, const float* __restrict__ W,
    _Float16* __restrict__ XP0, _Float16* __restrict__ XP0T) {
  constexpr int WR = O / 64;      // 2 for O=128, 1 for O=64
  constexpr int WC = 4 / WR;      // 2 or 4
  constexpr int TN = WC * 64;     // 128 or 256
  constexpr int NPT = TN / 64;    // staging chunks per thread (2 or 4)
  __shared__ _Float16 ldsB[2][TN * 32];
  const int tid = threadIdx.x;
  const int c0 = blockIdx.x * TN;  // global col base (b*1024+j), within one b
  const int b = c0 >> 10;
  const int l = tid & 63;
  const int w = tid >> 6;
  const int wr = w / WC, wc = w % WC;

  f16x8 af[4][3];
#pragma unroll
  for (int i = 0; i < 4; ++i) {
    int o = wr * 64 + i * 16 + (l & 15);
#pragma unroll
    for (int ks = 0; ks < 3; ++ks) {
#pragma unroll
      for (int e = 0; e < 8; ++e) {
        int f = ks * 32 + (l >> 4) * 8 + e;
        af[i][ks][e] = (f < 66) ? (_Float16)W[f * O + o] : (_Float16)0.f;
      }
    }
  }

  int tt[NPT], rr[NPT], qq[NPT];
#pragma unroll
  for (int u = 0; u < NPT; ++u) {
    tt[u] = u * 256 + tid;
    rr[u] = tt[u] >> 2;
    qq[u] = (tt[u] & 3) ^ (rr[u] & 3);
  }

  const int ps = ((l >> 4) ^ (l & 3)) * 8;
  int offB[4];
#pragma unroll
  for (int j = 0; j < 4; ++j)
    offB[j] = (wc * 64 + j * 16 + (l & 15)) * 32 + ps;

  f32x4 acc[4][4];
#pragma unroll
  for (int i = 0; i < 4; ++i)
#pragma unroll
    for (int j = 0; j < 4; ++j) acc[i][j] = (f32x4){0.f, 0.f, 0.f, 0.f};

#pragma unroll
  for (int u = 0; u < NPT; ++u)
    load_lds16(X0P + (size_t)(c0 + rr[u]) * 96 + qq[u] * 8,
               &ldsB[0][0] + tt[u] * 8);

  int buf = 0;
  for (int kt = 0; kt < 3; ++kt) {
    __syncthreads();
    if (kt + 1 < 3) {
#pragma unroll
      for (int u = 0; u < NPT; ++u)
        load_lds16(X0P + (size_t)(c0 + rr[u]) * 96 + (kt + 1) * 32 + qq[u] * 8,
                   &ldsB[buf ^ 1][0] + tt[u] * 8);
    }
    f16x8 bf[4];
#pragma unroll
    for (int j = 0; j < 4; ++j) bf[j] = *(const f16x8*)(&ldsB[buf][offB[j]]);
#pragma unroll
    for (int i = 0; i < 4; ++i)
#pragma unroll
      for (int j = 0; j < 4; ++j)
        acc[i][j] = __builtin_amdgcn_mfma_f32_16x16x32_f16(af[i][kt], bf[j],
                                                           acc[i][j], 0, 0, 0);
    buf ^= 1;
  }

#pragma unroll
  for (int i = 0; i < 4; ++i) {
    int ob = wr * 64 + i * 16 + (l >> 4) * 4;  // 4 consecutive o
#pragma unroll
    for (int j = 0; j < 4; ++j) {
      int jn = (c0 & 1023) + wc * 64 + j * 16 + (l & 15);
      f16x4 hv;
#pragma unroll
      for (int r = 0; r < 4; ++r) {
        hv[r] = (_Float16)acc[i][j][r];
        XP0T[((size_t)b * O + ob + r) * 1024 + jn] = hv[r];
      }
      *(f16x4*)(XP0 + ((size_t)jn * 32 + b) * O + ob) = hv;
    }
  }
}

// ---------------------------------------------------------------------------
// K3: supports GEMM (round-8 proven form: 16x16x32, 128x128 tile, BK=32,
// 4 waves 2x2) with launch_bounds(256,4) to target 4 blocks/CU
// (unified regs ~120 <= 128/wave at 4 waves/SIMD; LDS 32KB*4 <= 160KB).
// XPD[(m*1024+i)][c] = sum_j A_m[i][j] * XP0T[c][j],  c = b*O+o, CN=32*O.
// ---------------------------------------------------------------------------
template <int CN>
__global__ __launch_bounds__(256, 4) void k_supports2_mfma(
    const _Float16* __restrict__ A, const _Float16* __restrict__ BT,
    _Float16* __restrict__ XPD) {
  __shared__ _Float16 ldsA[2][4096];  // [buf][128 rows][32 k]
  __shared__ _Float16 ldsB[2][4096];
  const int tid = threadIdx.x;
  const int bn = blockIdx.x;  // col tiles (CN/128)
  const int bm = blockIdx.y;  // 0..79
  const int l = tid & 63;
  const int w = tid >> 6;
  const int wr = w >> 1, wc = w & 1;

  const int t0 = tid, t1 = 256 + tid;
  const int r0 = t0 >> 2, q0 = (t0 & 3) ^ (r0 & 3);
  const int r1 = t1 >> 2, q1 = (t1 & 3) ^ (r1 & 3);
  const _Float16* gA0 = A + ((size_t)(bm * 128 + r0)) * 1024 + q0 * 8;
  const _Float16* gA1 = A + ((size_t)(bm * 128 + r1)) * 1024 + q1 * 8;
  const _Float16* gB0 = BT + ((size_t)(bn * 128 + r0)) * 1024 + q0 * 8;
  const _Float16* gB1 = BT + ((size_t)(bn * 128 + r1)) * 1024 + q1 * 8;

  const int ps = ((l >> 4) ^ (l & 3)) * 8;
  int offA[4], offB[4];
#pragma unroll
  for (int i = 0; i < 4; ++i) {
    offA[i] = (wr * 64 + i * 16 + (l & 15)) * 32 + ps;
    offB[i] = (wc * 64 + i * 16 + (l & 15)) * 32 + ps;
  }

  f32x4 acc[4][4];
#pragma unroll
  for (int i = 0; i < 4; ++i)
#pragma unroll
    for (int j = 0; j < 4; ++j) acc[i][j] = (f32x4){0.f, 0.f, 0.f, 0.f};

  load_lds16(gA0, &ldsA[0][0] + t0 * 8);
  load_lds16(gA1, &ldsA[0][0] + t1 * 8);
  load_lds16(gB0, &ldsB[0][0] + t0 * 8);
  load_lds16(gB1, &ldsB[0][0] + t1 * 8);

  int buf = 0;
  for (int kt = 0; kt < 32; ++kt) {
    __syncthreads();
    if (kt + 1 < 32) {
      int k0 = (kt + 1) * 32;
      load_lds16(gA0 + k0, &ldsA[buf ^ 1][0] + t0 * 8);
      load_lds16(gA1 + k0, &ldsA[buf ^ 1][0] + t1 * 8);
      load_lds16(gB0 + k0, &ldsB[buf ^ 1][0] + t0 * 8);
      load_lds16(gB1 + k0, &ldsB[buf ^ 1][0] + t1 * 8);
    }
    f16x8 af[4], bf[4];
#pragma unroll
    for (int i = 0; i < 4; ++i)
      af[i] = *(const f16x8*)(&ldsA[buf][offA[i]]);
#pragma unroll
    for (int i = 0; i < 4; ++i)
      bf[i] = *(const f16x8*)(&ldsB[buf][offB[i]]);
#pragma unroll
    for (int i = 0; i < 4; ++i)
#pragma unroll
      for (int j = 0; j < 4; ++j)
        acc[i][j] = __builtin_amdgcn_mfma_f32_16x16x32_f16(af[i], bf[j],
                                                           acc[i][j], 0, 0, 0);
    buf ^= 1;
  }

#pragma unroll
  for (int i = 0; i < 4; ++i) {
    int R = bm * 128 + wr * 64 + i * 16 + (l >> 4) * 4;
#pragma unroll
    for (int j = 0; j < 4; ++j) {
      int col = bn * 128 + wc * 64 + j * 16 + (l & 15);
#pragma unroll
      for (int r = 0; r < 4; ++r)
        XPD[(size_t)(R + r) * CN + col] = (_Float16)acc[i][j][r];
    }
  }
}

// ---------------------------------------------------------------------------
// K4: attention via MFMA (reads XPD rows [(s'*1024+n)][CN], s'=g*5+si).
// Staging now 16B-chunk vectorized (f16x8); swizzle operates on 16B slots so
// values/layout are bit-identical to the u32 version.
// Writes xi/xs as fp16 hi+lo into CAT2h/CAT2l [(n*32+b)][2*O].
// ---------------------------------------------------------------------------
template <int O>
__global__ __launch_bounds__(256) void k_attend_mfma(
    const __half* __restrict__ XPD, const float* __restrict__ Watt,
    const float* __restrict__ Watt1, _Float16* __restrict__ CAT2h,
    _Float16* __restrict__ CAT2l) {
  constexpr int MTW = O / 64;       // q-tiles per wave (2 or 1)
  constexpr int KS = O / 32;        // k-steps (4 or 2)
  constexpr int SLOTS = O / 8;      // 16B slots per row (16 or 8)
  constexpr int SWZ = SLOTS - 1;
  const int n = blockIdx.x;
  const int tid = threadIdx.x;
  const int l = tid & 63;
  const int w = tid >> 6;

  __shared__ _Float16 xpL[160 * O];
  __shared__ float sPartL[4][160];
  __shared__ float aL[32][5];

  const int qbase = w * (O / 4);
  f16x8 afr[MTW][KS];
#pragma unroll
  for (int mt = 0; mt < MTW; ++mt) {
    const int q = qbase + mt * 16 + (l & 15);
#pragma unroll
    for (int ks = 0; ks < KS; ++ks) {
#pragma unroll
      for (int e = 0; e < 8; ++e) {
        int o = ks * 32 + (l >> 4) * 8 + e;
        afr[mt][ks][e] = (_Float16)Watt[((size_t)n * O + o) * O + q];
      }
    }
  }
  float wt1[MTW][4];
#pragma unroll
  for (int mt = 0; mt < MTW; ++mt)
#pragma unroll
    for (int r = 0; r < 4; ++r)
      wt1[mt][r] = Watt1[(size_t)n * O + qbase + mt * 16 + (l >> 4) * 4 + r];

  for (int g = 0; g < 2; ++g) {
    if (g) __syncthreads();
    {
      const f16x8* xsrc = reinterpret_cast<const f16x8*>(XPD);
      f16x8* xdst = reinterpret_cast<f16x8*>(xpL);
      for (int p = tid; p < 160 * SLOTS; p += 256) {
        int row = p / SLOTS;
        int sc = p - row * SLOTS;
        int phys = sc ^ (row & SWZ);
        int si = row >> 5, b = row & 31;
        size_t gi = ((size_t)(g * 5 + si) * 1024 + n) * (size_t)(4 * O) +
                    b * (O / 8) + sc;
        xdst[row * SLOTS + phys] = xsrc[gi];
      }
    }
    __syncthreads();

    for (int nt = 0; nt < 10; ++nt) {
      f32x4 acc[MTW];
#pragma unroll
      for (int mt = 0; mt < MTW; ++mt) acc[mt] = (f32x4){0.f, 0.f, 0.f, 0.f};
      const int row = nt * 16 + (l & 15);
#pragma unroll
      for (int ks = 0; ks < KS; ++ks) {
        int phys = (ks * 4 + (l >> 4)) ^ (row & SWZ);
        f16x8 bf = *(const f16x8*)(&xpL[row * O + phys * 8]);
#pragma unroll
        for (int mt = 0; mt < MTW; ++mt)
          acc[mt] = __builtin_amdgcn_mfma_f32_16x16x32_f16(afr[mt][ks], bf,
                                                           acc[mt], 0, 0, 0);
      }
      float sp = 0.f;
#pragma unroll
      for (int mt = 0; mt < MTW; ++mt)
#pragma unroll
        for (int r = 0; r < 4; ++r)
          sp += fmaxf(acc[mt][r], 0.f) * wt1[mt][r];
      sp += __shfl_xor(sp, 16);
      sp += __shfl_xor(sp, 32);
      if (l < 16) sPartL[w][nt * 16 + l] = sp;
    }
    __syncthreads();

    if (tid < 32) {
      const int b = tid;
      float sv[5];
#pragma unroll
      for (int k = 0; k < 5; ++k) {
        int row = k * 32 + b;
        sv[k] = sPartL[0][row] + sPartL[1][row] + sPartL[2][row] +
                sPartL[3][row];
      }
      float mx = sv[0];
#pragma unroll
      for (int k = 1; k < 5; ++k) mx = fmaxf(mx, sv[k]);
      float e[5], sum = 0.f;
#pragma unroll
      for (int k = 0; k < 5; ++k) {
        e[k] = expf(sv[k] - mx);
        sum += e[k];
      }
      float inv = 1.f / sum;
#pragma unroll
      for (int k = 0; k < 5; ++k) aL[b][k] = e[k] * inv;
    }
    __syncthreads();

    for (int it = 0; it < SLOTS * 32 / 256; ++it) {
      int idx = it * 256 + tid;
      int b = idx & 31;
      int sc = idx >> 5;
      float o8[8] = {0.f, 0.f, 0.f, 0.f, 0.f, 0.f, 0.f, 0.f};
#pragma unroll
      for (int si = 0; si < 5; ++si) {
        int row = si * 32 + b;
        int phys = sc ^ (row & SWZ);
        f16x8 xv = *(const f16x8*)(&xpL[row * O + phys * 8]);
        float a = aL[b][si];
#pragma unroll
        for (int j = 0; j < 8; ++j) o8[j] += a * (float)xv[j];
      }
      f16x8 hv, lv;
#pragma unroll
      for (int j = 0; j < 8; ++j) {
        hv[j] = (_Float16)o8[j];
        lv[j] = (_Float16)(o8[j] - (float)hv[j]);
      }
      size_t doff = ((size_t)n * 32 + b) * (2 * O) + g * O + sc * 8;
      *reinterpret_cast<f16x8*>(CAT2h + doff) = hv;
      *reinterpret_cast<f16x8*>(CAT2l + doff) = lv;
    }
  }
}

// ---------------------------------------------------------------------------
// K5: ru Wout GEMM via split-fp16 MFMA + fused sigmoid.
// ---------------------------------------------------------------------------
__global__ __launch_bounds__(256, 2) void k_wout_ru_mfma(
    const _Float16* __restrict__ CAT2h, const _Float16* __restrict__ CAT2l,
    const _Float16* __restrict__ XP0, const _Float16* __restrict__ WTh,
    const _Float16* __restrict__ WTl, const float* __restrict__ bias,
    const float* __restrict__ hx, float* __restrict__ RHX,
    float* __restrict__ UBUF) {
  constexpr int KTOT = 384, KC = 8, KT = 12;
  __shared__ _Float16 ldsAh[2][4096];
  __shared__ _Float16 ldsAl[2][4096];
  __shared__ _Float16 ldsBh[2][4096];
  __shared__ _Float16 ldsBl[2][4096];
  const int tid = threadIdx.x;
  const int blk = blockIdx.x;
  const int l = tid & 63;
  const int w = tid >> 6;
  const int wr = w >> 1, wc = w & 1;

  const int t0 = tid, t1 = 256 + tid;
  const int r0 = t0 >> 2, q0 = (t0 & 3) ^ (r0 & 3);
  const int r1 = t1 >> 2, q1 = (t1 & 3) ^ (r1 & 3);
  const size_t R0 = (size_t)blk * 128 + r0, R1 = (size_t)blk * 128 + r1;
  const _Float16* pA0ch = CAT2h + R0 * 256 + q0 * 8;
  const _Float16* pA1ch = CAT2h + R1 * 256 + q1 * 8;
  const _Float16* pA0cl = CAT2l + R0 * 256 + q0 * 8;
  const _Float16* pA1cl = CAT2l + R1 * 256 + q1 * 8;
  const _Float16* pA0x = XP0 + R0 * 128 + q0 * 8;
  const _Float16* pA1x = XP0 + R1 * 128 + q1 * 8;
  const _Float16* pB0h = WTh + (size_t)r0 * KTOT + q0 * 8;
  const _Float16* pB1h = WTh + (size_t)r1 * KTOT + q1 * 8;
  const _Float16* pB0l = WTl + (size_t)r0 * KTOT + q0 * 8;
  const _Float16* pB1l = WTl + (size_t)r1 * KTOT + q1 * 8;

  const int ps = ((l >> 4) ^ (l & 3)) * 8;
  int offA[4], offB[4];
#pragma unroll
  for (int i = 0; i < 4; ++i) {
    offA[i] = (wr * 64 + i * 16 + (l & 15)) * 32 + ps;
    offB[i] = (wc * 64 + i * 16 + (l & 15)) * 32 + ps;
  }

  f32x4 acc[4][4];
#pragma unroll
  for (int i = 0; i < 4; ++i)
#pragma unroll
    for (int j = 0; j < 4; ++j) acc[i][j] = (f32x4){0.f, 0.f, 0.f, 0.f};

  load_lds16(pA0ch, &ldsAh[0][0] + t0 * 8);
  load_lds16(pA1ch, &ldsAh[0][0] + t1 * 8);
  load_lds16(pA0cl, &ldsAl[0][0] + t0 * 8);
  load_lds16(pA1cl, &ldsAl[0][0] + t1 * 8);
  load_lds16(pB0h, &ldsBh[0][0] + t0 * 8);
  load_lds16(pB1h, &ldsBh[0][0] + t1 * 8);
  load_lds16(pB0l, &ldsBl[0][0] + t0 * 8);
  load_lds16(pB1l, &ldsBl[0][0] + t1 * 8);

  int buf = 0;
  for (int kt = 0; kt < KT; ++kt) {
    __syncthreads();
    if (kt + 1 < KT) {
      int k1 = kt + 1;
      const _Float16* a0 =
          (k1 < KC) ? pA0ch + k1 * 32 : pA0x + (k1 - KC) * 32;
      const _Float16* a1 =
          (k1 < KC) ? pA1ch + k1 * 32 : pA1x + (k1 - KC) * 32;
      load_lds16(a0, &ldsAh[buf ^ 1][0] + t0 * 8);
      load_lds16(a1, &ldsAh[buf ^ 1][0] + t1 * 8);
      if (k1 < KC) {
        load_lds16(pA0cl + k1 * 32, &ldsAl[buf ^ 1][0] + t0 * 8);
        load_lds16(pA1cl + k1 * 32, &ldsAl[buf ^ 1][0] + t1 * 8);
      }
      load_lds16(pB0h + k1 * 32, &ldsBh[buf ^ 1][0] + t0 * 8);
      load_lds16(pB1h + k1 * 32, &ldsBh[buf ^ 1][0] + t1 * 8);
      load_lds16(pB0l + k1 * 32, &ldsBl[buf ^ 1][0] + t0 * 8);
      load_lds16(pB1l + k1 * 32, &ldsBl[buf ^ 1][0] + t1 * 8);
    }
    f16x8 ah[4], bh[4], bl[4];
#pragma unroll
    for (int i = 0; i < 4; ++i) ah[i] = *(const f16x8*)(&ldsAh[buf][offA[i]]);
#pragma unroll
    for (int i = 0; i < 4; ++i) bh[i] = *(const f16x8*)(&ldsBh[buf][offB[i]]);
#pragma unroll
    for (int i = 0; i < 4; ++i) bl[i] = *(const f16x8*)(&ldsBl[buf][offB[i]]);
#pragma unroll
    for (int i = 0; i < 4; ++i)
#pragma unroll
      for (int j = 0; j < 4; ++j) {
        acc[i][j] = __builtin_amdgcn_mfma_f32_16x16x32_f16(ah[i], bh[j],
                                                           acc[i][j], 0, 0, 0);
        acc[i][j] = __builtin_amdgcn_mfma_f32_16x16x32_f16(ah[i], bl[j],
                                                           acc[i][j], 0, 0, 0);
      }
    if (kt < KC) {
      f16x8 al[4];
#pragma unroll
      for (int i = 0; i < 4; ++i)
        al[i] = *(const f16x8*)(&ldsAl[buf][offA[i]]);
#pragma unroll
      for (int i = 0; i < 4; ++i)
#pragma unroll
        for (int j = 0; j < 4; ++j)
          acc[i][j] = __builtin_amdgcn_mfma_f32_16x16x32_f16(al[i], bh[j],
                                                             acc[i][j], 0, 0, 0);
    }
    buf ^= 1;
  }

#pragma unroll
  for (int i = 0; i < 4; ++i) {
    int R = blk * 128 + wr * 64 + i * 16 + (l >> 4) * 4;
#pragma unroll
    for (int j = 0; j < 4; ++j) {
      int o = wc * 64 + j * 16 + (l & 15);
      float bv = bias[o];
#pragma unroll
      for (int rr = 0; rr < 4; ++rr) {
        int Rr = R + rr;
        int n = Rr >> 5, b = Rr & 31;
        size_t base = ((size_t)b * NN + n) * 64;
        float val = 1.f / (1.f + expf(-(acc[i][j][rr] + bv)));
        if (o < 64)
          RHX[base + o] = val * hx[base + o];
        else
          UBUF[base + (o - 64)] = val;
      }
    }
  }
}

// ---------------------------------------------------------------------------
// K6: candidate Wout GEMM (plain fp16 MFMA; terminal op) + tanh + gate -> out.
// ---------------------------------------------------------------------------
__global__ __launch_bounds__(256, 2) void k_wout_c_mfma(
    const _Float16* __restrict__ CAT2h, const _Float16* __restrict__ XP0,
    const _Float16* __restrict__ WTh, const float* __restrict__ bias,
    const float* __restrict__ UBUF, const float* __restrict__ hx,
    float* __restrict__ out) {
  constexpr int KTOT = 192, KC = 4, KT = 6;
  __shared__ _Float16 ldsAh[2][4096];
  __shared__ _Float16 ldsBh[2][2048];
  const int tid = threadIdx.x;
  const int blk = blockIdx.x;
  const int l = tid & 63;
  const int w = tid >> 6;

  const int t0 = tid, t1 = 256 + tid;
  const int r0 = t0 >> 2, q0 = (t0 & 3) ^ (r0 & 3);
  const int r1 = t1 >> 2, q1 = (t1 & 3) ^ (r1 & 3);
  const size_t R0 = (size_t)blk * 128 + r0, R1 = (size_t)blk * 128 + r1;
  const _Float16* pA0ch = CAT2h + R0 * 128 + q0 * 8;
  const _Float16* pA1ch = CAT2h + R1 * 128 + q1 * 8;
  const _Float16* pA0x = XP0 + R0 * 64 + q0 * 8;
  const _Float16* pA1x = XP0 + R1 * 64 + q1 * 8;
  const int rb = tid >> 2, qb = (tid & 3) ^ (rb & 3);
  const _Float16* pBh = WTh + (size_t)rb * KTOT + qb * 8;

  const int ps = ((l >> 4) ^ (l & 3)) * 8;
  int offA[2], offB[4];
#pragma unroll
  for (int i = 0; i < 2; ++i)
    offA[i] = (w * 32 + i * 16 + (l & 15)) * 32 + ps;
#pragma unroll
  for (int j = 0; j < 4; ++j) offB[j] = (j * 16 + (l & 15)) * 32 + ps;

  f32x4 acc[2][4];
#pragma unroll
  for (int i = 0; i < 2; ++i)
#pragma unroll
    for (int j = 0; j < 4; ++j) acc[i][j] = (f32x4){0.f, 0.f, 0.f, 0.f};

  load_lds16(pA0ch, &ldsAh[0][0] + t0 * 8);
  load_lds16(pA1ch, &ldsAh[0][0] + t1 * 8);
  load_lds16(pBh, &ldsBh[0][0] + tid * 8);

  int buf = 0;
  for (int kt = 0; kt < KT; ++kt) {
    __syncthreads();
    if (kt + 1 < KT) {
      int k1 = kt + 1;
      const _Float16* a0 =
          (k1 < KC) ? pA0ch + k1 * 32 : pA0x + (k1 - KC) * 32;
      const _Float16* a1 =
          (k1 < KC) ? pA1ch + k1 * 32 : pA1x + (k1 - KC) * 32;
      load_lds16(a0, &ldsAh[buf ^ 1][0] + t0 * 8);
      load_lds16(a1, &ldsAh[buf ^ 1][0] + t1 * 8);
      load_lds16(pBh + k1 * 32, &ldsBh[buf ^ 1][0] + tid * 8);
    }
    f16x8 ah[2], bh[4];
#pragma unroll
    for (int i = 0; i < 2; ++i) ah[i] = *(const f16x8*)(&ldsAh[buf][offA[i]]);
#pragma unroll
    for (int j = 0; j < 4; ++j) bh[j] = *(const f16x8*)(&ldsBh[buf][offB[j]]);
#pragma unroll
    for (int i = 0; i < 2; ++i)
#pragma unroll
      for (int j = 0; j < 4; ++j)
        acc[i][j] = __builtin_amdgcn_mfma_f32_16x16x32_f16(ah[i], bh[j],
                                                           acc[i][j], 0, 0, 0);
    buf ^= 1;
  }

#pragma unroll
  for (int i = 0; i < 2; ++i) {
    int R = blk * 128 + w * 32 + i * 16 + (l >> 4) * 4;
#pragma unroll
    for (int j = 0; j < 4; ++j) {
      int o = j * 16 + (l & 15);
      float bv = bias[o];
#pragma unroll
      for (int rr = 0; rr < 4; ++rr) {
        int Rr = R + rr;
        int n = Rr >> 5, b = Rr & 31;
        size_t idx = ((size_t)b * NN + n) * 64 + o;
        float cval = tanhf(acc[i][j][rr] + bv);
        float u = UBUF[idx];
        out[idx] = u * hx[idx] + (1.f - u) * cval;
      }
    }
  }
}

// ---------------------------------------------------------------------------
extern "C" void kernel_launch(void* const* d_in, const int* in_sizes, int n_in,
                              void* d_out, int out_size, void* d_ws,
                              size_t ws_size, hipStream_t stream) {
  const float* inputs   = (const float*)d_in[0];
  const float* hx       = (const float*)d_in[1];
  const float* adj      = (const float*)d_in[2];
  const float* mask     = (const float*)d_in[3];
  const float* W_ru     = (const float*)d_in[4];
  const float* Watt_ru  = (const float*)d_in[5];
  const float* Watt1_ru = (const float*)d_in[6];
  const float* Wout_ru  = (const float*)d_in[7];
  const float* b_ru     = (const float*)d_in[8];
  const float* W_c      = (const float*)d_in[9];
  const float* Watt_c   = (const float*)d_in[10];
  const float* Watt1_c  = (const float*)d_in[11];
  const float* Wout_c   = (const float*)d_in[12];
  const float* b_c      = (const float*)d_in[13];

  // workspace arena (~178.5 MB), same as round 6/8
  char* ws = (char*)d_ws;
  _Float16*  X0P   = (_Float16*)(ws);
  _Float16*  XPD   = (_Float16*)(ws + 6291456);
  _Float16*  XP0   = (_Float16*)(ws + 90177536);
  _Float16*  XP0T  = (_Float16*)(ws + 98566144);
  _Float16*  CAT2h = (_Float16*)(ws + 106954752);
  _Float16*  CAT2l = (_Float16*)(ws + 123731968);
  float*     RHX   = (float*)(ws + 140509184);
  float*     UBUF  = (float*)(ws + 148897792);
  _Float16*  A_all = (_Float16*)(ws + 157286400);
  _Float16*  WThru = (_Float16*)(ws + 178257920);
  _Float16*  WTlru = (_Float16*)(ws + 178356224);
  _Float16*  WThc  = (_Float16*)(ws + 178454528);
  _Float16*  WTlc  = (_Float16*)(ws + 178479104);
  float*     out   = (float*)d_out;

  k_build_amats<<<1024, 256, 0, stream>>>(adj, mask, A_all);
  k_prep_wout<<<240, 256, 0, stream>>>(Wout_ru, Wout_c, WThru, WTlru, WThc,
                                       WTlc);

  // ---- gate gconv (O = 2U = 128) ----
  k_build_x0p<<<dim3(32, 16), 256, 0, stream>>>(inputs, hx, X0P);
  k_proj0_mfma<128><<<256, 256, 0, stream>>>(X0P, W_ru, XP0, XP0T);
  k_supports2_mfma<4096><<<dim3(32, 80), 256, 0, stream>>>(A_all, XP0T, XPD);
  k_attend_mfma<128><<<1024, 256, 0, stream>>>((const __half*)XPD, Watt_ru,
                                               Watt1_ru, CAT2h, CAT2l);
  k_wout_ru_mfma<<<256, 256, 0, stream>>>(CAT2h, CAT2l, XP0, WThru, WTlru,
                                          b_ru, hx, RHX, UBUF);
  // ---- candidate gconv (O = U = 64), state = r*hx ----
  k_build_x0p<<<dim3(32, 16), 256, 0, stream>>>(inputs, RHX, X0P);
  k_proj0_mfma<64><<<128, 256, 0, stream>>>(X0P, W_c, XP0, XP0T);
  k_supports2_mfma<2048><<<dim3(16, 80), 256, 0, stream>>>(A_all, XP0T, XPD);
  k_attend_mfma<64><<<1024, 256, 0, stream>>>((const __half*)XPD, Watt_c,
                                              Watt1_c, CAT2h, CAT2l);
  k_wout_c_mfma<<<256, 256, 0, stream>>>(CAT2h, XP0, WThc, b_c,
                                         UBUF, hx, out);
}

// Round 11
// 316.382 us; speedup vs baseline: 1.1331x; 1.0747x over previous
//
#include <hip/hip_runtime.h>
#include <hip/hip_fp16.h>
#include <cstdint>
#include <cstddef>

#define NN 1024   // nodes
#define BB 32     // batch

typedef _Float16 f16x8 __attribute__((ext_vector_type(8)));
typedef _Float16 f16x4 __attribute__((ext_vector_type(4)));
typedef float f32x4 __attribute__((ext_vector_type(4)));

__device__ __forceinline__ void load_lds16(const void* g, void* l) {
  __builtin_amdgcn_global_load_lds(
      (const __attribute__((address_space(1))) void*)g,
      (__attribute__((address_space(3))) void*)l, 16, 0, 0);
}

// ---------------------------------------------------------------------------
// K0: merged prep — blocks <1024: build the 10 support matrices (fp16);
// blocks >=1024: transpose+convert Wout matrices to fp16 hi/lo [O][K].
// ---------------------------------------------------------------------------
__global__ __launch_bounds__(256) void k_prep(
    const float* __restrict__ adj, const float* __restrict__ mask,
    _Float16* __restrict__ A, const float* __restrict__ Wru,
    const float* __restrict__ Wc, _Float16* __restrict__ WThru,
    _Float16* __restrict__ WTlru, _Float16* __restrict__ WThc,
    _Float16* __restrict__ WTlc) {
  const int bid = blockIdx.x;
  const int tid = threadIdx.x;
  if (bid < 1024) {
    int q = bid * 256 + tid;  // 0..262143 quads
    int i = q >> 8;
    int j0 = (q & 255) << 2;
    size_t off = (size_t)i * 1024 + j0;
    float4 a0 = *(const float4*)(adj + off);
    float4 a1 = *(const float4*)(adj + (1u << 20) + off);
    f16x4 r;
    r[0] = a0.x; r[1] = a0.y; r[2] = a0.z; r[3] = a0.w;
    *(f16x4*)(A + off) = r;
    r[0] = a1.x; r[1] = a1.y; r[2] = a1.z; r[3] = a1.w;
    *(f16x4*)(A + (size_t)9 * 1048576 + off) = r;
#pragma unroll
    for (int l = 0; l < 8; ++l) {
      float4 mk = *(const float4*)(mask + (size_t)l * 1048576 + off);
      float4 base = (l < 4) ? a0 : a1;
      r[0] = mk.x * base.x; r[1] = mk.y * base.y;
      r[2] = mk.z * base.z; r[3] = mk.w * base.w;
      *(f16x4*)(A + (size_t)(l + 1) * 1048576 + off) = r;
    }
  } else {
    int id = (bid - 1024) * 256 + tid;
    if (id < 128 * 384) {
      int o = id & 127, k = id >> 7;
      float w = Wru[k * 128 + o];
      _Float16 h = (_Float16)w;
      WThru[o * 384 + k] = h;
      WTlru[o * 384 + k] = (_Float16)(w - (float)h);
    } else {
      int id2 = id - 128 * 384;
      if (id2 < 64 * 192) {
        int o = id2 & 63, k = id2 >> 6;
        float w = Wc[k * 64 + o];
        _Float16 h = (_Float16)w;
        WThc[o * 192 + k] = h;
        WTlc[o * 192 + k] = (_Float16)(w - (float)h);
      }
    }
  }
}

// ---------------------------------------------------------------------------
// K2: fused build+proj0 GEMM via MFMA.
// XP0[(j*32+b)][o] = sum_f x[b,j,f] * W[f,o]; also XP0T[(b*O+o)][j].
// Block = TN rows (j) of one b; builds its fp16 swizzled LDS tile directly
// from inputs/state (fp32) — X0P intermediate eliminated.
// ---------------------------------------------------------------------------
template <int O>
__global__ __launch_bounds__(256, 2) void k_proj0_fused(
    const float* __restrict__ inp, const float* __restrict__ state,
    const float* __restrict__ W, _Float16* __restrict__ XP0,
    _Float16* __restrict__ XP0T) {
  constexpr int WR = O / 64;      // 2 for O=128, 1 for O=64
  constexpr int WC = 4 / WR;      // 2 or 4
  constexpr int TN = WC * 64;     // 128 or 256
  constexpr int TPR = 256 / TN;   // threads per row: 2 or 1
  __shared__ _Float16 ldsX[TN * 96];  // [row][96 halfs], chunk-swizzled
  const int tid = threadIdx.x;
  const int c0 = blockIdx.x * TN;  // global (b*1024+j) base, within one b
  const int b = c0 >> 10;
  const int l = tid & 63;
  const int w = tid >> 6;
  const int wr = w / WC, wc = w % WC;

  // A-frags (W^T) in registers, zero-padded f>=66
  f16x8 af[4][3];
#pragma unroll
  for (int i = 0; i < 4; ++i) {
    int o = wr * 64 + i * 16 + (l & 15);
#pragma unroll
    for (int ks = 0; ks < 3; ++ks) {
#pragma unroll
      for (int e = 0; e < 8; ++e) {
        int f = ks * 32 + (l >> 4) * 8 + e;
        af[i][ks][e] = (f < 66) ? (_Float16)W[f * O + o] : (_Float16)0.f;
      }
    }
  }

  // ---- build LDS rows from inputs/state (fp32 -> fp16, chunk-swizzled) ----
  {
    const int row = (TPR == 2) ? (tid >> 1) : tid;
    const int h = (TPR == 2) ? (tid & 1) : 0;
    const int j = (c0 & 1023) + row;
    const float* sp = state + (size_t)b * 65536 + (size_t)j * 64;
    _Float16* ldsRow = ldsX + row * 96;
    const int rsw = row & 3;
    // chunk c (0..11) holds halfs p=c*8..c*8+7; stored at section kt=c>>2,
    // phys slot (c&3)^(row&3)  (matches frag-read swizzle)
    if (TPR == 1 || h == 0) {
      float2 in2 = *(const float2*)(inp + (size_t)b * 2048 + j * 2);
      float sv[48];
#pragma unroll
      for (int u = 0; u < 12; ++u)
        *(f32x4*)(sv + u * 4) = *(const f32x4*)(sp + u * 4);
      f16x8 v;
      v[0] = (_Float16)in2.x;
      v[1] = (_Float16)in2.y;
#pragma unroll
      for (int e = 2; e < 8; ++e) v[e] = (_Float16)sv[e - 2];
      *(f16x8*)(ldsRow + ((0 ^ rsw) << 3)) = v;
#pragma unroll
      for (int c = 1; c < 6; ++c) {
#pragma unroll
        for (int e = 0; e < 8; ++e) v[e] = (_Float16)sv[c * 8 + e - 2];
        int kt = c >> 2, cq = c & 3;
        *(f16x8*)(ldsRow + kt * 32 + ((cq ^ rsw) << 3)) = v;
      }
    }
    if (TPR == 1 || h == 1) {
      float sv2[20];  // s44..s63
#pragma unroll
      for (int u = 0; u < 5; ++u)
        *(f32x4*)(sv2 + u * 4) = *(const f32x4*)(sp + 44 + u * 4);
      f16x8 v;
#pragma unroll
      for (int e = 0; e < 8; ++e) v[e] = (_Float16)sv2[2 + e];  // s46..53
      *(f16x8*)(ldsRow + 32 + ((2 ^ rsw) << 3)) = v;            // c=6
#pragma unroll
      for (int e = 0; e < 8; ++e) v[e] = (_Float16)sv2[10 + e];  // s54..61
      *(f16x8*)(ldsRow + 32 + ((3 ^ rsw) << 3)) = v;             // c=7
      v[0] = (_Float16)sv2[18];
      v[1] = (_Float16)sv2[19];
#pragma unroll
      for (int e = 2; e < 8; ++e) v[e] = (_Float16)0.f;
      *(f16x8*)(ldsRow + 64 + ((0 ^ rsw) << 3)) = v;  // c=8
#pragma unroll
      for (int e = 0; e < 8; ++e) v[e] = (_Float16)0.f;
      *(f16x8*)(ldsRow + 64 + ((1 ^ rsw) << 3)) = v;  // c=9
      *(f16x8*)(ldsRow + 64 + ((2 ^ rsw) << 3)) = v;  // c=10
      *(f16x8*)(ldsRow + 64 + ((3 ^ rsw) << 3)) = v;  // c=11
    }
  }
  __syncthreads();

  const int ps = ((l >> 4) ^ (l & 3)) * 8;
  int offB[4];
#pragma unroll
  for (int j = 0; j < 4; ++j)
    offB[j] = (wc * 64 + j * 16 + (l & 15)) * 96 + ps;

  f32x4 acc[4][4];
#pragma unroll
  for (int i = 0; i < 4; ++i)
#pragma unroll
    for (int j = 0; j < 4; ++j) acc[i][j] = (f32x4){0.f, 0.f, 0.f, 0.f};

#pragma unroll
  for (int kt = 0; kt < 3; ++kt) {
    f16x8 bf[4];
#pragma unroll
    for (int j = 0; j < 4; ++j)
      bf[j] = *(const f16x8*)(&ldsX[offB[j] + kt * 32]);
#pragma unroll
    for (int i = 0; i < 4; ++i)
#pragma unroll
      for (int j = 0; j < 4; ++j)
        acc[i][j] = __builtin_amdgcn_mfma_f32_16x16x32_f16(af[i][kt], bf[j],
                                                           acc[i][j], 0, 0, 0);
  }

#pragma unroll
  for (int i = 0; i < 4; ++i) {
    int ob = wr * 64 + i * 16 + (l >> 4) * 4;  // 4 consecutive o
#pragma unroll
    for (int j = 0; j < 4; ++j) {
      int jn = (c0 & 1023) + wc * 64 + j * 16 + (l & 15);
      f16x4 hv;
#pragma unroll
      for (int r = 0; r < 4; ++r) {
        hv[r] = (_Float16)acc[i][j][r];
        XP0T[((size_t)b * O + ob + r) * 1024 + jn] = hv[r];
      }
      *(f16x4*)(XP0 + ((size_t)jn * 32 + b) * O + ob) = hv;
    }
  }
}

// ---------------------------------------------------------------------------
// K3: supports GEMM (round-8 proven K-loop: 16x16x32, 128x128 tile, BK=32,
// 4 waves 2x2) + NEW coalesced epilogue (acc -> swizzled LDS -> f16x8
// contiguous stores; replaces 64 scattered 2B stores per thread with 8x 16B).
// XPD[(m*1024+i)][c] = sum_j A_m[i][j] * XP0T[c][j],  c = b*O+o, CN=32*O.
// ---------------------------------------------------------------------------
template <int CN>
__global__ __launch_bounds__(256, 2) void k_supports2_mfma(
    const _Float16* __restrict__ A, const _Float16* __restrict__ BT,
    _Float16* __restrict__ XPD) {
  __shared__ _Float16 ldsU[4][4096];  // [0..1]=A bufs, [2..3]=B bufs
  const int tid = threadIdx.x;
  const int bn = blockIdx.x;  // col tiles (CN/128)
  const int bm = blockIdx.y;  // 0..79
  const int l = tid & 63;
  const int w = tid >> 6;
  const int wr = w >> 1, wc = w & 1;

  const int t0 = tid, t1 = 256 + tid;
  const int r0 = t0 >> 2, q0 = (t0 & 3) ^ (r0 & 3);
  const int r1 = t1 >> 2, q1 = (t1 & 3) ^ (r1 & 3);
  const _Float16* gA0 = A + ((size_t)(bm * 128 + r0)) * 1024 + q0 * 8;
  const _Float16* gA1 = A + ((size_t)(bm * 128 + r1)) * 1024 + q1 * 8;
  const _Float16* gB0 = BT + ((size_t)(bn * 128 + r0)) * 1024 + q0 * 8;
  const _Float16* gB1 = BT + ((size_t)(bn * 128 + r1)) * 1024 + q1 * 8;

  const int ps = ((l >> 4) ^ (l & 3)) * 8;
  int offA[4], offB[4];
#pragma unroll
  for (int i = 0; i < 4; ++i) {
    offA[i] = (wr * 64 + i * 16 + (l & 15)) * 32 + ps;
    offB[i] = (wc * 64 + i * 16 + (l & 15)) * 32 + ps;
  }

  f32x4 acc[4][4];
#pragma unroll
  for (int i = 0; i < 4; ++i)
#pragma unroll
    for (int j = 0; j < 4; ++j) acc[i][j] = (f32x4){0.f, 0.f, 0.f, 0.f};

  load_lds16(gA0, &ldsU[0][0] + t0 * 8);
  load_lds16(gA1, &ldsU[0][0] + t1 * 8);
  load_lds16(gB0, &ldsU[2][0] + t0 * 8);
  load_lds16(gB1, &ldsU[2][0] + t1 * 8);

  int buf = 0;
  for (int kt = 0; kt < 32; ++kt) {
    __syncthreads();
    if (kt + 1 < 32) {
      int k0 = (kt + 1) * 32;
      load_lds16(gA0 + k0, &ldsU[buf ^ 1][0] + t0 * 8);
      load_lds16(gA1 + k0, &ldsU[buf ^ 1][0] + t1 * 8);
      load_lds16(gB0 + k0, &ldsU[2 + (buf ^ 1)][0] + t0 * 8);
      load_lds16(gB1 + k0, &ldsU[2 + (buf ^ 1)][0] + t1 * 8);
    }
    f16x8 af[4], bf[4];
#pragma unroll
    for (int i = 0; i < 4; ++i)
      af[i] = *(const f16x8*)(&ldsU[buf][offA[i]]);
#pragma unroll
    for (int i = 0; i < 4; ++i)
      bf[i] = *(const f16x8*)(&ldsU[2 + buf][offB[i]]);
#pragma unroll
    for (int i = 0; i < 4; ++i)
#pragma unroll
      for (int j = 0; j < 4; ++j)
        acc[i][j] = __builtin_amdgcn_mfma_f32_16x16x32_f16(af[i], bf[j],
                                                           acc[i][j], 0, 0, 0);
    buf ^= 1;
  }

  // ---- coalesced epilogue via swizzled LDS transpose ----
  __syncthreads();  // all ds_reads of the K-loop complete
  {
    _Float16* C = &ldsU[0][0];  // 128x128 fp16 = 32KB
#pragma unroll
    for (int i = 0; i < 4; ++i) {
      int Rl = wr * 64 + i * 16 + (l >> 4) * 4;
#pragma unroll
      for (int j = 0; j < 4; ++j) {
        int Cc = wc * 64 + j * 16 + (l & 15);
#pragma unroll
        for (int r = 0; r < 4; ++r) {
          int row = Rl + r;
          C[row * 128 + (((Cc >> 3) ^ (row & 7)) << 3) + (Cc & 7)] =
              (_Float16)acc[i][j][r];
        }
      }
    }
    __syncthreads();
#pragma unroll
    for (int it = 0; it < 8; ++it) {
      int flat = it * 256 + tid;
      int row = flat >> 4;
      int c2 = flat & 15;
      f16x8 v = *(const f16x8*)(&C[row * 128 + ((c2 ^ (row & 7)) << 3)]);
      *(f16x8*)(XPD + (size_t)(bm * 128 + row) * CN + bn * 128 + c2 * 8) = v;
    }
  }
}

// ---------------------------------------------------------------------------
// K4: attention via MFMA (unchanged from round 10).
// ---------------------------------------------------------------------------
template <int O>
__global__ __launch_bounds__(256) void k_attend_mfma(
    const __half* __restrict__ XPD, const float* __restrict__ Watt,
    const float* __restrict__ Watt1, _Float16* __restrict__ CAT2h,
    _Float16* __restrict__ CAT2l) {
  constexpr int MTW = O / 64;       // q-tiles per wave (2 or 1)
  constexpr int KS = O / 32;        // k-steps (4 or 2)
  constexpr int SLOTS = O / 8;      // 16B slots per row (16 or 8)
  constexpr int SWZ = SLOTS - 1;
  const int n = blockIdx.x;
  const int tid = threadIdx.x;
  const int l = tid & 63;
  const int w = tid >> 6;

  __shared__ _Float16 xpL[160 * O];
  __shared__ float sPartL[4][160];
  __shared__ float aL[32][5];

  const int qbase = w * (O / 4);
  f16x8 afr[MTW][KS];
#pragma unroll
  for (int mt = 0; mt < MTW; ++mt) {
    const int q = qbase + mt * 16 + (l & 15);
#pragma unroll
    for (int ks = 0; ks < KS; ++ks) {
#pragma unroll
      for (int e = 0; e < 8; ++e) {
        int o = ks * 32 + (l >> 4) * 8 + e;
        afr[mt][ks][e] = (_Float16)Watt[((size_t)n * O + o) * O + q];
      }
    }
  }
  float wt1[MTW][4];
#pragma unroll
  for (int mt = 0; mt < MTW; ++mt)
#pragma unroll
    for (int r = 0; r < 4; ++r)
      wt1[mt][r] = Watt1[(size_t)n * O + qbase + mt * 16 + (l >> 4) * 4 + r];

  for (int g = 0; g < 2; ++g) {
    if (g) __syncthreads();
    {
      const f16x8* xsrc = reinterpret_cast<const f16x8*>(XPD);
      f16x8* xdst = reinterpret_cast<f16x8*>(xpL);
      for (int p = tid; p < 160 * SLOTS; p += 256) {
        int row = p / SLOTS;
        int sc = p - row * SLOTS;
        int phys = sc ^ (row & SWZ);
        int si = row >> 5, b = row & 31;
        size_t gi = ((size_t)(g * 5 + si) * 1024 + n) * (size_t)(4 * O) +
                    b * (O / 8) + sc;
        xdst[row * SLOTS + phys] = xsrc[gi];
      }
    }
    __syncthreads();

    for (int nt = 0; nt < 10; ++nt) {
      f32x4 acc[MTW];
#pragma unroll
      for (int mt = 0; mt < MTW; ++mt) acc[mt] = (f32x4){0.f, 0.f, 0.f, 0.f};
      const int row = nt * 16 + (l & 15);
#pragma unroll
      for (int ks = 0; ks < KS; ++ks) {
        int phys = (ks * 4 + (l >> 4)) ^ (row & SWZ);
        f16x8 bf = *(const f16x8*)(&xpL[row * O + phys * 8]);
#pragma unroll
        for (int mt = 0; mt < MTW; ++mt)
          acc[mt] = __builtin_amdgcn_mfma_f32_16x16x32_f16(afr[mt][ks], bf,
                                                           acc[mt], 0, 0, 0);
      }
      float sp = 0.f;
#pragma unroll
      for (int mt = 0; mt < MTW; ++mt)
#pragma unroll
        for (int r = 0; r < 4; ++r)
          sp += fmaxf(acc[mt][r], 0.f) * wt1[mt][r];
      sp += __shfl_xor(sp, 16);
      sp += __shfl_xor(sp, 32);
      if (l < 16) sPartL[w][nt * 16 + l] = sp;
    }
    __syncthreads();

    if (tid < 32) {
      const int b = tid;
      float sv[5];
#pragma unroll
      for (int k = 0; k < 5; ++k) {
        int row = k * 32 + b;
        sv[k] = sPartL[0][row] + sPartL[1][row] + sPartL[2][row] +
                sPartL[3][row];
      }
      float mx = sv[0];
#pragma unroll
      for (int k = 1; k < 5; ++k) mx = fmaxf(mx, sv[k]);
      float e[5], sum = 0.f;
#pragma unroll
      for (int k = 0; k < 5; ++k) {
        e[k] = expf(sv[k] - mx);
        sum += e[k];
      }
      float inv = 1.f / sum;
#pragma unroll
      for (int k = 0; k < 5; ++k) aL[b][k] = e[k] * inv;
    }
    __syncthreads();

    for (int it = 0; it < SLOTS * 32 / 256; ++it) {
      int idx = it * 256 + tid;
      int b = idx & 31;
      int sc = idx >> 5;
      float o8[8] = {0.f, 0.f, 0.f, 0.f, 0.f, 0.f, 0.f, 0.f};
#pragma unroll
      for (int si = 0; si < 5; ++si) {
        int row = si * 32 + b;
        int phys = sc ^ (row & SWZ);
        f16x8 xv = *(const f16x8*)(&xpL[row * O + phys * 8]);
        float a = aL[b][si];
#pragma unroll
        for (int j = 0; j < 8; ++j) o8[j] += a * (float)xv[j];
      }
      f16x8 hv, lv;
#pragma unroll
      for (int j = 0; j < 8; ++j) {
        hv[j] = (_Float16)o8[j];
        lv[j] = (_Float16)(o8[j] - (float)hv[j]);
      }
      size_t doff = ((size_t)n * 32 + b) * (2 * O) + g * O + sc * 8;
      *reinterpret_cast<f16x8*>(CAT2h + doff) = hv;
      *reinterpret_cast<f16x8*>(CAT2l + doff) = lv;
    }
  }
}

// ---------------------------------------------------------------------------
// K5: ru Wout GEMM via split-fp16 MFMA + fused sigmoid (unchanged).
// ---------------------------------------------------------------------------
__global__ __launch_bounds__(256, 2) void k_wout_ru_mfma(
    const _Float16* __restrict__ CAT2h, const _Float16* __restrict__ CAT2l,
    const _Float16* __restrict__ XP0, const _Float16* __restrict__ WTh,
    const _Float16* __restrict__ WTl, const float* __restrict__ bias,
    const float* __restrict__ hx, float* __restrict__ RHX,
    float* __restrict__ UBUF) {
  constexpr int KTOT = 384, KC = 8, KT = 12;
  __shared__ _Float16 ldsAh[2][4096];
  __shared__ _Float16 ldsAl[2][4096];
  __shared__ _Float16 ldsBh[2][4096];
  __shared__ _Float16 ldsBl[2][4096];
  const int tid = threadIdx.x;
  const int blk = blockIdx.x;
  const int l = tid & 63;
  const int w = tid >> 6;
  const int wr = w >> 1, wc = w & 1;

  const int t0 = tid, t1 = 256 + tid;
  const int r0 = t0 >> 2, q0 = (t0 & 3) ^ (r0 & 3);
  const int r1 = t1 >> 2, q1 = (t1 & 3) ^ (r1 & 3);
  const size_t R0 = (size_t)blk * 128 + r0, R1 = (size_t)blk * 128 + r1;
  const _Float16* pA0ch = CAT2h + R0 * 256 + q0 * 8;
  const _Float16* pA1ch = CAT2h + R1 * 256 + q1 * 8;
  const _Float16* pA0cl = CAT2l + R0 * 256 + q0 * 8;
  const _Float16* pA1cl = CAT2l + R1 * 256 + q1 * 8;
  const _Float16* pA0x = XP0 + R0 * 128 + q0 * 8;
  const _Float16* pA1x = XP0 + R1 * 128 + q1 * 8;
  const _Float16* pB0h = WTh + (size_t)r0 * KTOT + q0 * 8;
  const _Float16* pB1h = WTh + (size_t)r1 * KTOT + q1 * 8;
  const _Float16* pB0l = WTl + (size_t)r0 * KTOT + q0 * 8;
  const _Float16* pB1l = WTl + (size_t)r1 * KTOT + q1 * 8;

  const int ps = ((l >> 4) ^ (l & 3)) * 8;
  int offA[4], offB[4];
#pragma unroll
  for (int i = 0; i < 4; ++i) {
    offA[i] = (wr * 64 + i * 16 + (l & 15)) * 32 + ps;
    offB[i] = (wc * 64 + i * 16 + (l & 15)) * 32 + ps;
  }

  f32x4 acc[4][4];
#pragma unroll
  for (int i = 0; i < 4; ++i)
#pragma unroll
    for (int j = 0; j < 4; ++j) acc[i][j] = (f32x4){0.f, 0.f, 0.f, 0.f};

  load_lds16(pA0ch, &ldsAh[0][0] + t0 * 8);
  load_lds16(pA1ch, &ldsAh[0][0] + t1 * 8);
  load_lds16(pA0cl, &ldsAl[0][0] + t0 * 8);
  load_lds16(pA1cl, &ldsAl[0][0] + t1 * 8);
  load_lds16(pB0h, &ldsBh[0][0] + t0 * 8);
  load_lds16(pB1h, &ldsBh[0][0] + t1 * 8);
  load_lds16(pB0l, &ldsBl[0][0] + t0 * 8);
  load_lds16(pB1l, &ldsBl[0][0] + t1 * 8);

  int buf = 0;
  for (int kt = 0; kt < KT; ++kt) {
    __syncthreads();
    if (kt + 1 < KT) {
      int k1 = kt + 1;
      const _Float16* a0 =
          (k1 < KC) ? pA0ch + k1 * 32 : pA0x + (k1 - KC) * 32;
      const _Float16* a1 =
          (k1 < KC) ? pA1ch + k1 * 32 : pA1x + (k1 - KC) * 32;
      load_lds16(a0, &ldsAh[buf ^ 1][0] + t0 * 8);
      load_lds16(a1, &ldsAh[buf ^ 1][0] + t1 * 8);
      if (k1 < KC) {
        load_lds16(pA0cl + k1 * 32, &ldsAl[buf ^ 1][0] + t0 * 8);
        load_lds16(pA1cl + k1 * 32, &ldsAl[buf ^ 1][0] + t1 * 8);
      }
      load_lds16(pB0h + k1 * 32, &ldsBh[buf ^ 1][0] + t0 * 8);
      load_lds16(pB1h + k1 * 32, &ldsBh[buf ^ 1][0] + t1 * 8);
      load_lds16(pB0l + k1 * 32, &ldsBl[buf ^ 1][0] + t0 * 8);
      load_lds16(pB1l + k1 * 32, &ldsBl[buf ^ 1][0] + t1 * 8);
    }
    f16x8 ah[4], bh[4], bl[4];
#pragma unroll
    for (int i = 0; i < 4; ++i) ah[i] = *(const f16x8*)(&ldsAh[buf][offA[i]]);
#pragma unroll
    for (int i = 0; i < 4; ++i) bh[i] = *(const f16x8*)(&ldsBh[buf][offB[i]]);
#pragma unroll
    for (int i = 0; i < 4; ++i) bl[i] = *(const f16x8*)(&ldsBl[buf][offB[i]]);
#pragma unroll
    for (int i = 0; i < 4; ++i)
#pragma unroll
      for (int j = 0; j < 4; ++j) {
        acc[i][j] = __builtin_amdgcn_mfma_f32_16x16x32_f16(ah[i], bh[j],
                                                           acc[i][j], 0, 0, 0);
        acc[i][j] = __builtin_amdgcn_mfma_f32_16x16x32_f16(ah[i], bl[j],
                                                           acc[i][j], 0, 0, 0);
      }
    if (kt < KC) {
      f16x8 al[4];
#pragma unroll
      for (int i = 0; i < 4; ++i)
        al[i] = *(const f16x8*)(&ldsAl[buf][offA[i]]);
#pragma unroll
      for (int i = 0; i < 4; ++i)
#pragma unroll
        for (int j = 0; j < 4; ++j)
          acc[i][j] = __builtin_amdgcn_mfma_f32_16x16x32_f16(al[i], bh[j],
                                                             acc[i][j], 0, 0, 0);
    }
    buf ^= 1;
  }

#pragma unroll
  for (int i = 0; i < 4; ++i) {
    int R = blk * 128 + wr * 64 + i * 16 + (l >> 4) * 4;
#pragma unroll
    for (int j = 0; j < 4; ++j) {
      int o = wc * 64 + j * 16 + (l & 15);
      float bv = bias[o];
#pragma unroll
      for (int rr = 0; rr < 4; ++rr) {
        int Rr = R + rr;
        int n = Rr >> 5, b = Rr & 31;
        size_t base = ((size_t)b * NN + n) * 64;
        float val = 1.f / (1.f + expf(-(acc[i][j][rr] + bv)));
        if (o < 64)
          RHX[base + o] = val * hx[base + o];
        else
          UBUF[base + (o - 64)] = val;
      }
    }
  }
}

// ---------------------------------------------------------------------------
// K6: candidate Wout GEMM (plain fp16 MFMA; terminal op) + tanh + gate -> out.
// ---------------------------------------------------------------------------
__global__ __launch_bounds__(256, 2) void k_wout_c_mfma(
    const _Float16* __restrict__ CAT2h, const _Float16* __restrict__ XP0,
    const _Float16* __restrict__ WTh, const float* __restrict__ bias,
    const float* __restrict__ UBUF, const float* __restrict__ hx,
    float* __restrict__ out) {
  constexpr int KTOT = 192, KC = 4, KT = 6;
  __shared__ _Float16 ldsAh[2][4096];
  __shared__ _Float16 ldsBh[2][2048];
  const int tid = threadIdx.x;
  const int blk = blockIdx.x;
  const int l = tid & 63;
  const int w = tid >> 6;

  const int t0 = tid, t1 = 256 + tid;
  const int r0 = t0 >> 2, q0 = (t0 & 3) ^ (r0 & 3);
  const int r1 = t1 >> 2, q1 = (t1 & 3) ^ (r1 & 3);
  const size_t R0 = (size_t)blk * 128 + r0, R1 = (size_t)blk * 128 + r1;
  const _Float16* pA0ch = CAT2h + R0 * 128 + q0 * 8;
  const _Float16* pA1ch = CAT2h + R1 * 128 + q1 * 8;
  const _Float16* pA0x = XP0 + R0 * 64 + q0 * 8;
  const _Float16* pA1x = XP0 + R1 * 64 + q1 * 8;
  const int rb = tid >> 2, qb = (tid & 3) ^ (rb & 3);
  const _Float16* pBh = WTh + (size_t)rb * KTOT + qb * 8;

  const int ps = ((l >> 4) ^ (l & 3)) * 8;
  int offA[2], offB[4];
#pragma unroll
  for (int i = 0; i < 2; ++i)
    offA[i] = (w * 32 + i * 16 + (l & 15)) * 32 + ps;
#pragma unroll
  for (int j = 0; j < 4; ++j) offB[j] = (j * 16 + (l & 15)) * 32 + ps;

  f32x4 acc[2][4];
#pragma unroll
  for (int i = 0; i < 2; ++i)
#pragma unroll
    for (int j = 0; j < 4; ++j) acc[i][j] = (f32x4){0.f, 0.f, 0.f, 0.f};

  load_lds16(pA0ch, &ldsAh[0][0] + t0 * 8);
  load_lds16(pA1ch, &ldsAh[0][0] + t1 * 8);
  load_lds16(pBh, &ldsBh[0][0] + tid * 8);

  int buf = 0;
  for (int kt = 0; kt < KT; ++kt) {
    __syncthreads();
    if (kt + 1 < KT) {
      int k1 = kt + 1;
      const _Float16* a0 =
          (k1 < KC) ? pA0ch + k1 * 32 : pA0x + (k1 - KC) * 32;
      const _Float16* a1 =
          (k1 < KC) ? pA1ch + k1 * 32 : pA1x + (k1 - KC) * 32;
      load_lds16(a0, &ldsAh[buf ^ 1][0] + t0 * 8);
      load_lds16(a1, &ldsAh[buf ^ 1][0] + t1 * 8);
      load_lds16(pBh + k1 * 32, &ldsBh[buf ^ 1][0] + tid * 8);
    }
    f16x8 ah[2], bh[4];
#pragma unroll
    for (int i = 0; i < 2; ++i) ah[i] = *(const f16x8*)(&ldsAh[buf][offA[i]]);
#pragma unroll
    for (int j = 0; j < 4; ++j) bh[j] = *(const f16x8*)(&ldsBh[buf][offB[j]]);
#pragma unroll
    for (int i = 0; i < 2; ++i)
#pragma unroll
      for (int j = 0; j < 4; ++j)
        acc[i][j] = __builtin_amdgcn_mfma_f32_16x16x32_f16(ah[i], bh[j],
                                                           acc[i][j], 0, 0, 0);
    buf ^= 1;
  }

#pragma unroll
  for (int i = 0; i < 2; ++i) {
    int R = blk * 128 + w * 32 + i * 16 + (l >> 4) * 4;
#pragma unroll
    for (int j = 0; j < 4; ++j) {
      int o = j * 16 + (l & 15);
      float bv = bias[o];
#pragma unroll
      for (int rr = 0; rr < 4; ++rr) {
        int Rr = R + rr;
        int n = Rr >> 5, b = Rr & 31;
        size_t idx = ((size_t)b * NN + n) * 64 + o;
        float cval = tanhf(acc[i][j][rr] + bv);
        float u = UBUF[idx];
        out[idx] = u * hx[idx] + (1.f - u) * cval;
      }
    }
  }
}

// ---------------------------------------------------------------------------
extern "C" void kernel_launch(void* const* d_in, const int* in_sizes, int n_in,
                              void* d_out, int out_size, void* d_ws,
                              size_t ws_size, hipStream_t stream) {
  const float* inputs   = (const float*)d_in[0];
  const float* hx       = (const float*)d_in[1];
  const float* adj      = (const float*)d_in[2];
  const float* mask     = (const float*)d_in[3];
  const float* W_ru     = (const float*)d_in[4];
  const float* Watt_ru  = (const float*)d_in[5];
  const float* Watt1_ru = (const float*)d_in[6];
  const float* Wout_ru  = (const float*)d_in[7];
  const float* b_ru     = (const float*)d_in[8];
  const float* W_c      = (const float*)d_in[9];
  const float* Watt_c   = (const float*)d_in[10];
  const float* Watt1_c  = (const float*)d_in[11];
  const float* Wout_c   = (const float*)d_in[12];
  const float* b_c      = (const float*)d_in[13];

  // workspace arena (~178.5 MB), offsets unchanged (X0P slot now unused)
  char* ws = (char*)d_ws;
  _Float16*  XPD   = (_Float16*)(ws + 6291456);
  _Float16*  XP0   = (_Float16*)(ws + 90177536);
  _Float16*  XP0T  = (_Float16*)(ws + 98566144);
  _Float16*  CAT2h = (_Float16*)(ws + 106954752);
  _Float16*  CAT2l = (_Float16*)(ws + 123731968);
  float*     RHX   = (float*)(ws + 140509184);
  float*     UBUF  = (float*)(ws + 148897792);
  _Float16*  A_all = (_Float16*)(ws + 157286400);
  _Float16*  WThru = (_Float16*)(ws + 178257920);
  _Float16*  WTlru = (_Float16*)(ws + 178356224);
  _Float16*  WThc  = (_Float16*)(ws + 178454528);
  _Float16*  WTlc  = (_Float16*)(ws + 178479104);
  float*     out   = (float*)d_out;

  k_prep<<<1264, 256, 0, stream>>>(adj, mask, A_all, Wout_ru, Wout_c, WThru,
                                   WTlru, WThc, WTlc);

  // ---- gate gconv (O = 2U = 128) ----
  k_proj0_fused<128><<<256, 256, 0, stream>>>(inputs, hx, W_ru, XP0, XP0T);
  k_supports2_mfma<4096><<<dim3(32, 80), 256, 0, stream>>>(A_all, XP0T, XPD);
  k_attend_mfma<128><<<1024, 256, 0, stream>>>((const __half*)XPD, Watt_ru,
                                               Watt1_ru, CAT2h, CAT2l);
  k_wout_ru_mfma<<<256, 256, 0, stream>>>(CAT2h, CAT2l, XP0, WThru, WTlru,
                                          b_ru, hx, RHX, UBUF);
  // ---- candidate gconv (O = U = 64), state = r*hx ----
  k_proj0_fused<64><<<128, 256, 0, stream>>>(inputs, RHX, W_c, XP0, XP0T);
  k_supports2_mfma<2048><<<dim3(16, 80), 256, 0, stream>>>(A_all, XP0T, XPD);
  k_attend_mfma<64><<<1024, 256, 0, stream>>>((const __half*)XPD, Watt_c,
                                              Watt1_c, CAT2h, CAT2l);
  k_wout_c_mfma<<<256, 256, 0, stream>>>(CAT2h, XP0, WThc, b_c,
                                         UBUF, hx, out);
}

// Round 12
// 312.559 us; speedup vs baseline: 1.1470x; 1.0122x over previous
//
#include <hip/hip_runtime.h>
#include <hip/hip_fp16.h>
#include <cstdint>
#include <cstddef>

#define NN 1024   // nodes
#define BB 32     // batch

typedef _Float16 f16x8 __attribute__((ext_vector_type(8)));
typedef _Float16 f16x4 __attribute__((ext_vector_type(4)));
typedef float f32x4 __attribute__((ext_vector_type(4)));

__device__ __forceinline__ void load_lds16(const void* g, void* l) {
  __builtin_amdgcn_global_load_lds(
      (const __attribute__((address_space(1))) void*)g,
      (__attribute__((address_space(3))) void*)l, 16, 0, 0);
}

// ---------------------------------------------------------------------------
// prep body: bid<1024 -> build 10 support matrices (fp16);
// bid>=1024 -> transpose+convert Wout matrices to fp16 hi/lo [O][K].
// ---------------------------------------------------------------------------
__device__ __forceinline__ void prep_body(
    int bid, int tid, const float* __restrict__ adj,
    const float* __restrict__ mask, _Float16* __restrict__ A,
    const float* __restrict__ Wru, const float* __restrict__ Wc,
    _Float16* __restrict__ WThru, _Float16* __restrict__ WTlru,
    _Float16* __restrict__ WThc, _Float16* __restrict__ WTlc) {
  if (bid < 1024) {
    int q = bid * 256 + tid;  // 0..262143 quads
    int i = q >> 8;
    int j0 = (q & 255) << 2;
    size_t off = (size_t)i * 1024 + j0;
    float4 a0 = *(const float4*)(adj + off);
    float4 a1 = *(const float4*)(adj + (1u << 20) + off);
    f16x4 r;
    r[0] = a0.x; r[1] = a0.y; r[2] = a0.z; r[3] = a0.w;
    *(f16x4*)(A + off) = r;
    r[0] = a1.x; r[1] = a1.y; r[2] = a1.z; r[3] = a1.w;
    *(f16x4*)(A + (size_t)9 * 1048576 + off) = r;
#pragma unroll
    for (int l = 0; l < 8; ++l) {
      float4 mk = *(const float4*)(mask + (size_t)l * 1048576 + off);
      float4 base = (l < 4) ? a0 : a1;
      r[0] = mk.x * base.x; r[1] = mk.y * base.y;
      r[2] = mk.z * base.z; r[3] = mk.w * base.w;
      *(f16x4*)(A + (size_t)(l + 1) * 1048576 + off) = r;
    }
  } else {
    int id = (bid - 1024) * 256 + tid;
    if (id < 128 * 384) {
      int o = id & 127, k = id >> 7;
      float w = Wru[k * 128 + o];
      _Float16 h = (_Float16)w;
      WThru[o * 384 + k] = h;
      WTlru[o * 384 + k] = (_Float16)(w - (float)h);
    } else {
      int id2 = id - 128 * 384;
      if (id2 < 64 * 192) {
        int o = id2 & 63, k = id2 >> 6;
        float w = Wc[k * 64 + o];
        _Float16 h = (_Float16)w;
        WThc[o * 192 + k] = h;
        WTlc[o * 192 + k] = (_Float16)(w - (float)h);
      }
    }
  }
}

// ---------------------------------------------------------------------------
// proj0 body (fused build+proj GEMM via MFMA).
// XP0[(j*32+b)][o] = sum_f x[b,j,f] * W[f,o]; also XP0T[(b*O+o)][j].
// ---------------------------------------------------------------------------
template <int O>
__device__ __forceinline__ void proj0_body(
    int bx, const float* __restrict__ inp, const float* __restrict__ state,
    const float* __restrict__ W, _Float16* __restrict__ XP0,
    _Float16* __restrict__ XP0T) {
  constexpr int WR = O / 64;      // 2 for O=128, 1 for O=64
  constexpr int WC = 4 / WR;      // 2 or 4
  constexpr int TN = WC * 64;     // 128 or 256
  constexpr int TPR = 256 / TN;   // threads per row: 2 or 1
  __shared__ _Float16 ldsX[TN * 96];  // [row][96 halfs], chunk-swizzled
  const int tid = threadIdx.x;
  const int c0 = bx * TN;  // global (b*1024+j) base, within one b
  const int b = c0 >> 10;
  const int l = tid & 63;
  const int w = tid >> 6;
  const int wr = w / WC, wc = w % WC;

  // A-frags (W^T) in registers, zero-padded f>=66
  f16x8 af[4][3];
#pragma unroll
  for (int i = 0; i < 4; ++i) {
    int o = wr * 64 + i * 16 + (l & 15);
#pragma unroll
    for (int ks = 0; ks < 3; ++ks) {
#pragma unroll
      for (int e = 0; e < 8; ++e) {
        int f = ks * 32 + (l >> 4) * 8 + e;
        af[i][ks][e] = (f < 66) ? (_Float16)W[f * O + o] : (_Float16)0.f;
      }
    }
  }

  // ---- build LDS rows from inputs/state (fp32 -> fp16, chunk-swizzled) ----
  {
    const int row = (TPR == 2) ? (tid >> 1) : tid;
    const int h = (TPR == 2) ? (tid & 1) : 0;
    const int j = (c0 & 1023) + row;
    const float* sp = state + (size_t)b * 65536 + (size_t)j * 64;
    _Float16* ldsRow = ldsX + row * 96;
    const int rsw = row & 3;
    if (TPR == 1 || h == 0) {
      float2 in2 = *(const float2*)(inp + (size_t)b * 2048 + j * 2);
      float sv[48];
#pragma unroll
      for (int u = 0; u < 12; ++u)
        *(f32x4*)(sv + u * 4) = *(const f32x4*)(sp + u * 4);
      f16x8 v;
      v[0] = (_Float16)in2.x;
      v[1] = (_Float16)in2.y;
#pragma unroll
      for (int e = 2; e < 8; ++e) v[e] = (_Float16)sv[e - 2];
      *(f16x8*)(ldsRow + ((0 ^ rsw) << 3)) = v;
#pragma unroll
      for (int c = 1; c < 6; ++c) {
#pragma unroll
        for (int e = 0; e < 8; ++e) v[e] = (_Float16)sv[c * 8 + e - 2];
        int kt = c >> 2, cq = c & 3;
        *(f16x8*)(ldsRow + kt * 32 + ((cq ^ rsw) << 3)) = v;
      }
    }
    if (TPR == 1 || h == 1) {
      float sv2[20];  // s44..s63
#pragma unroll
      for (int u = 0; u < 5; ++u)
        *(f32x4*)(sv2 + u * 4) = *(const f32x4*)(sp + 44 + u * 4);
      f16x8 v;
#pragma unroll
      for (int e = 0; e < 8; ++e) v[e] = (_Float16)sv2[2 + e];  // s46..53
      *(f16x8*)(ldsRow + 32 + ((2 ^ rsw) << 3)) = v;            // c=6
#pragma unroll
      for (int e = 0; e < 8; ++e) v[e] = (_Float16)sv2[10 + e];  // s54..61
      *(f16x8*)(ldsRow + 32 + ((3 ^ rsw) << 3)) = v;             // c=7
      v[0] = (_Float16)sv2[18];
      v[1] = (_Float16)sv2[19];
#pragma unroll
      for (int e = 2; e < 8; ++e) v[e] = (_Float16)0.f;
      *(f16x8*)(ldsRow + 64 + ((0 ^ rsw) << 3)) = v;  // c=8
#pragma unroll
      for (int e = 0; e < 8; ++e) v[e] = (_Float16)0.f;
      *(f16x8*)(ldsRow + 64 + ((1 ^ rsw) << 3)) = v;  // c=9
      *(f16x8*)(ldsRow + 64 + ((2 ^ rsw) << 3)) = v;  // c=10
      *(f16x8*)(ldsRow + 64 + ((3 ^ rsw) << 3)) = v;  // c=11
    }
  }
  __syncthreads();

  const int ps = ((l >> 4) ^ (l & 3)) * 8;
  int offB[4];
#pragma unroll
  for (int j = 0; j < 4; ++j)
    offB[j] = (wc * 64 + j * 16 + (l & 15)) * 96 + ps;

  f32x4 acc[4][4];
#pragma unroll
  for (int i = 0; i < 4; ++i)
#pragma unroll
    for (int j = 0; j < 4; ++j) acc[i][j] = (f32x4){0.f, 0.f, 0.f, 0.f};

#pragma unroll
  for (int kt = 0; kt < 3; ++kt) {
    f16x8 bf[4];
#pragma unroll
    for (int j = 0; j < 4; ++j)
      bf[j] = *(const f16x8*)(&ldsX[offB[j] + kt * 32]);
#pragma unroll
    for (int i = 0; i < 4; ++i)
#pragma unroll
      for (int j = 0; j < 4; ++j)
        acc[i][j] = __builtin_amdgcn_mfma_f32_16x16x32_f16(af[i][kt], bf[j],
                                                           acc[i][j], 0, 0, 0);
  }

#pragma unroll
  for (int i = 0; i < 4; ++i) {
    int ob = wr * 64 + i * 16 + (l >> 4) * 4;  // 4 consecutive o
#pragma unroll
    for (int j = 0; j < 4; ++j) {
      int jn = (c0 & 1023) + wc * 64 + j * 16 + (l & 15);
      f16x4 hv;
#pragma unroll
      for (int r = 0; r < 4; ++r) {
        hv[r] = (_Float16)acc[i][j][r];
        XP0T[((size_t)b * O + ob + r) * 1024 + jn] = hv[r];
      }
      *(f16x4*)(XP0 + ((size_t)jn * 32 + b) * O + ob) = hv;
    }
  }
}

// ---------------------------------------------------------------------------
// K_front: blocks 0..255 = proj0<128> (gate); blocks 256..1519 = prep.
// prep is data-independent of proj0 -> co-scheduled, hides its HBM time.
// ---------------------------------------------------------------------------
__global__ __launch_bounds__(256, 2) void k_front(
    const float* __restrict__ inputs, const float* __restrict__ hx,
    const float* __restrict__ W_ru, _Float16* __restrict__ XP0,
    _Float16* __restrict__ XP0T, const float* __restrict__ adj,
    const float* __restrict__ mask, _Float16* __restrict__ A,
    const float* __restrict__ Wru, const float* __restrict__ Wc,
    _Float16* __restrict__ WThru, _Float16* __restrict__ WTlru,
    _Float16* __restrict__ WThc, _Float16* __restrict__ WTlc) {
  if (blockIdx.x < 256) {
    proj0_body<128>(blockIdx.x, inputs, hx, W_ru, XP0, XP0T);
  } else {
    prep_body(blockIdx.x - 256, threadIdx.x, adj, mask, A, Wru, Wc, WThru,
              WTlru, WThc, WTlc);
  }
}

// ---------------------------------------------------------------------------
// K2b: candidate proj0 (standalone; depends on RHX).
// ---------------------------------------------------------------------------
__global__ __launch_bounds__(256, 2) void k_proj0_c(
    const float* __restrict__ inp, const float* __restrict__ state,
    const float* __restrict__ W, _Float16* __restrict__ XP0,
    _Float16* __restrict__ XP0T) {
  proj0_body<64>(blockIdx.x, inp, state, W, XP0, XP0T);
}

// ---------------------------------------------------------------------------
// K3: supports GEMM (proven K-loop: 16x16x32, 128x128 tile, BK=32, 4 waves
// 2x2) + coalesced epilogue via swizzled LDS transpose.
// XPD[(m*1024+i)][c] = sum_j A_m[i][j] * XP0T[c][j],  c = b*O+o, CN=32*O.
// ---------------------------------------------------------------------------
template <int CN>
__global__ __launch_bounds__(256, 2) void k_supports2_mfma(
    const _Float16* __restrict__ A, const _Float16* __restrict__ BT,
    _Float16* __restrict__ XPD) {
  __shared__ _Float16 ldsU[4][4096];  // [0..1]=A bufs, [2..3]=B bufs
  const int tid = threadIdx.x;
  const int bn = blockIdx.x;  // col tiles (CN/128)
  const int bm = blockIdx.y;  // 0..79
  const int l = tid & 63;
  const int w = tid >> 6;
  const int wr = w >> 1, wc = w & 1;

  const int t0 = tid, t1 = 256 + tid;
  const int r0 = t0 >> 2, q0 = (t0 & 3) ^ (r0 & 3);
  const int r1 = t1 >> 2, q1 = (t1 & 3) ^ (r1 & 3);
  const _Float16* gA0 = A + ((size_t)(bm * 128 + r0)) * 1024 + q0 * 8;
  const _Float16* gA1 = A + ((size_t)(bm * 128 + r1)) * 1024 + q1 * 8;
  const _Float16* gB0 = BT + ((size_t)(bn * 128 + r0)) * 1024 + q0 * 8;
  const _Float16* gB1 = BT + ((size_t)(bn * 128 + r1)) * 1024 + q1 * 8;

  const int ps = ((l >> 4) ^ (l & 3)) * 8;
  int offA[4], offB[4];
#pragma unroll
  for (int i = 0; i < 4; ++i) {
    offA[i] = (wr * 64 + i * 16 + (l & 15)) * 32 + ps;
    offB[i] = (wc * 64 + i * 16 + (l & 15)) * 32 + ps;
  }

  f32x4 acc[4][4];
#pragma unroll
  for (int i = 0; i < 4; ++i)
#pragma unroll
    for (int j = 0; j < 4; ++j) acc[i][j] = (f32x4){0.f, 0.f, 0.f, 0.f};

  load_lds16(gA0, &ldsU[0][0] + t0 * 8);
  load_lds16(gA1, &ldsU[0][0] + t1 * 8);
  load_lds16(gB0, &ldsU[2][0] + t0 * 8);
  load_lds16(gB1, &ldsU[2][0] + t1 * 8);

  int buf = 0;
  for (int kt = 0; kt < 32; ++kt) {
    __syncthreads();
    if (kt + 1 < 32) {
      int k0 = (kt + 1) * 32;
      load_lds16(gA0 + k0, &ldsU[buf ^ 1][0] + t0 * 8);
      load_lds16(gA1 + k0, &ldsU[buf ^ 1][0] + t1 * 8);
      load_lds16(gB0 + k0, &ldsU[2 + (buf ^ 1)][0] + t0 * 8);
      load_lds16(gB1 + k0, &ldsU[2 + (buf ^ 1)][0] + t1 * 8);
    }
    f16x8 af[4], bf[4];
#pragma unroll
    for (int i = 0; i < 4; ++i)
      af[i] = *(const f16x8*)(&ldsU[buf][offA[i]]);
#pragma unroll
    for (int i = 0; i < 4; ++i)
      bf[i] = *(const f16x8*)(&ldsU[2 + buf][offB[i]]);
#pragma unroll
    for (int i = 0; i < 4; ++i)
#pragma unroll
      for (int j = 0; j < 4; ++j)
        acc[i][j] = __builtin_amdgcn_mfma_f32_16x16x32_f16(af[i], bf[j],
                                                           acc[i][j], 0, 0, 0);
    buf ^= 1;
  }

  // ---- coalesced epilogue via swizzled LDS transpose ----
  __syncthreads();  // all ds_reads of the K-loop complete
  {
    _Float16* C = &ldsU[0][0];  // 128x128 fp16 = 32KB
#pragma unroll
    for (int i = 0; i < 4; ++i) {
      int Rl = wr * 64 + i * 16 + (l >> 4) * 4;
#pragma unroll
      for (int j = 0; j < 4; ++j) {
        int Cc = wc * 64 + j * 16 + (l & 15);
#pragma unroll
        for (int r = 0; r < 4; ++r) {
          int row = Rl + r;
          C[row * 128 + (((Cc >> 3) ^ (row & 7)) << 3) + (Cc & 7)] =
              (_Float16)acc[i][j][r];
        }
      }
    }
    __syncthreads();
#pragma unroll
    for (int it = 0; it < 8; ++it) {
      int flat = it * 256 + tid;
      int row = flat >> 4;
      int c2 = flat & 15;
      f16x8 v = *(const f16x8*)(&C[row * 128 + ((c2 ^ (row & 7)) << 3)]);
      *(f16x8*)(XPD + (size_t)(bm * 128 + row) * CN + bn * 128 + c2 * 8) = v;
    }
  }
}

// ---------------------------------------------------------------------------
// K4: attention via MFMA (unchanged).
// ---------------------------------------------------------------------------
template <int O>
__global__ __launch_bounds__(256) void k_attend_mfma(
    const __half* __restrict__ XPD, const float* __restrict__ Watt,
    const float* __restrict__ Watt1, _Float16* __restrict__ CAT2h,
    _Float16* __restrict__ CAT2l) {
  constexpr int MTW = O / 64;       // q-tiles per wave (2 or 1)
  constexpr int KS = O / 32;        // k-steps (4 or 2)
  constexpr int SLOTS = O / 8;      // 16B slots per row (16 or 8)
  constexpr int SWZ = SLOTS - 1;
  const int n = blockIdx.x;
  const int tid = threadIdx.x;
  const int l = tid & 63;
  const int w = tid >> 6;

  __shared__ _Float16 xpL[160 * O];
  __shared__ float sPartL[4][160];
  __shared__ float aL[32][5];

  const int qbase = w * (O / 4);
  f16x8 afr[MTW][KS];
#pragma unroll
  for (int mt = 0; mt < MTW; ++mt) {
    const int q = qbase + mt * 16 + (l & 15);
#pragma unroll
    for (int ks = 0; ks < KS; ++ks) {
#pragma unroll
      for (int e = 0; e < 8; ++e) {
        int o = ks * 32 + (l >> 4) * 8 + e;
        afr[mt][ks][e] = (_Float16)Watt[((size_t)n * O + o) * O + q];
      }
    }
  }
  float wt1[MTW][4];
#pragma unroll
  for (int mt = 0; mt < MTW; ++mt)
#pragma unroll
    for (int r = 0; r < 4; ++r)
      wt1[mt][r] = Watt1[(size_t)n * O + qbase + mt * 16 + (l >> 4) * 4 + r];

  for (int g = 0; g < 2; ++g) {
    if (g) __syncthreads();
    {
      const f16x8* xsrc = reinterpret_cast<const f16x8*>(XPD);
      f16x8* xdst = reinterpret_cast<f16x8*>(xpL);
      for (int p = tid; p < 160 * SLOTS; p += 256) {
        int row = p / SLOTS;
        int sc = p - row * SLOTS;
        int phys = sc ^ (row & SWZ);
        int si = row >> 5, b = row & 31;
        size_t gi = ((size_t)(g * 5 + si) * 1024 + n) * (size_t)(4 * O) +
                    b * (O / 8) + sc;
        xdst[row * SLOTS + phys] = xsrc[gi];
      }
    }
    __syncthreads();

    for (int nt = 0; nt < 10; ++nt) {
      f32x4 acc[MTW];
#pragma unroll
      for (int mt = 0; mt < MTW; ++mt) acc[mt] = (f32x4){0.f, 0.f, 0.f, 0.f};
      const int row = nt * 16 + (l & 15);
#pragma unroll
      for (int ks = 0; ks < KS; ++ks) {
        int phys = (ks * 4 + (l >> 4)) ^ (row & SWZ);
        f16x8 bf = *(const f16x8*)(&xpL[row * O + phys * 8]);
#pragma unroll
        for (int mt = 0; mt < MTW; ++mt)
          acc[mt] = __builtin_amdgcn_mfma_f32_16x16x32_f16(afr[mt][ks], bf,
                                                           acc[mt], 0, 0, 0);
      }
      float sp = 0.f;
#pragma unroll
      for (int mt = 0; mt < MTW; ++mt)
#pragma unroll
        for (int r = 0; r < 4; ++r)
          sp += fmaxf(acc[mt][r], 0.f) * wt1[mt][r];
      sp += __shfl_xor(sp, 16);
      sp += __shfl_xor(sp, 32);
      if (l < 16) sPartL[w][nt * 16 + l] = sp;
    }
    __syncthreads();

    if (tid < 32) {
      const int b = tid;
      float sv[5];
#pragma unroll
      for (int k = 0; k < 5; ++k) {
        int row = k * 32 + b;
        sv[k] = sPartL[0][row] + sPartL[1][row] + sPartL[2][row] +
                sPartL[3][row];
      }
      float mx = sv[0];
#pragma unroll
      for (int k = 1; k < 5; ++k) mx = fmaxf(mx, sv[k]);
      float e[5], sum = 0.f;
#pragma unroll
      for (int k = 0; k < 5; ++k) {
        e[k] = expf(sv[k] - mx);
        sum += e[k];
      }
      float inv = 1.f / sum;
#pragma unroll
      for (int k = 0; k < 5; ++k) aL[b][k] = e[k] * inv;
    }
    __syncthreads();

    for (int it = 0; it < SLOTS * 32 / 256; ++it) {
      int idx = it * 256 + tid;
      int b = idx & 31;
      int sc = idx >> 5;
      float o8[8] = {0.f, 0.f, 0.f, 0.f, 0.f, 0.f, 0.f, 0.f};
#pragma unroll
      for (int si = 0; si < 5; ++si) {
        int row = si * 32 + b;
        int phys = sc ^ (row & SWZ);
        f16x8 xv = *(const f16x8*)(&xpL[row * O + phys * 8]);
        float a = aL[b][si];
#pragma unroll
        for (int j = 0; j < 8; ++j) o8[j] += a * (float)xv[j];
      }
      f16x8 hv, lv;
#pragma unroll
      for (int j = 0; j < 8; ++j) {
        hv[j] = (_Float16)o8[j];
        lv[j] = (_Float16)(o8[j] - (float)hv[j]);
      }
      size_t doff = ((size_t)n * 32 + b) * (2 * O) + g * O + sc * 8;
      *reinterpret_cast<f16x8*>(CAT2h + doff) = hv;
      *reinterpret_cast<f16x8*>(CAT2l + doff) = lv;
    }
  }
}

// ---------------------------------------------------------------------------
// K5: ru Wout GEMM via split-fp16 MFMA + fused sigmoid (unchanged).
// ---------------------------------------------------------------------------
__global__ __launch_bounds__(256, 2) void k_wout_ru_mfma(
    const _Float16* __restrict__ CAT2h, const _Float16* __restrict__ CAT2l,
    const _Float16* __restrict__ XP0, const _Float16* __restrict__ WTh,
    const _Float16* __restrict__ WTl, const float* __restrict__ bias,
    const float* __restrict__ hx, float* __restrict__ RHX,
    float* __restrict__ UBUF) {
  constexpr int KTOT = 384, KC = 8, KT = 12;
  __shared__ _Float16 ldsAh[2][4096];
  __shared__ _Float16 ldsAl[2][4096];
  __shared__ _Float16 ldsBh[2][4096];
  __shared__ _Float16 ldsBl[2][4096];
  const int tid = threadIdx.x;
  const int blk = blockIdx.x;
  const int l = tid & 63;
  const int w = tid >> 6;
  const int wr = w >> 1, wc = w & 1;

  const int t0 = tid, t1 = 256 + tid;
  const int r0 = t0 >> 2, q0 = (t0 & 3) ^ (r0 & 3);
  const int r1 = t1 >> 2, q1 = (t1 & 3) ^ (r1 & 3);
  const size_t R0 = (size_t)blk * 128 + r0, R1 = (size_t)blk * 128 + r1;
  const _Float16* pA0ch = CAT2h + R0 * 256 + q0 * 8;
  const _Float16* pA1ch = CAT2h + R1 * 256 + q1 * 8;
  const _Float16* pA0cl = CAT2l + R0 * 256 + q0 * 8;
  const _Float16* pA1cl = CAT2l + R1 * 256 + q1 * 8;
  const _Float16* pA0x = XP0 + R0 * 128 + q0 * 8;
  const _Float16* pA1x = XP0 + R1 * 128 + q1 * 8;
  const _Float16* pB0h = WTh + (size_t)r0 * KTOT + q0 * 8;
  const _Float16* pB1h = WTh + (size_t)r1 * KTOT + q1 * 8;
  const _Float16* pB0l = WTl + (size_t)r0 * KTOT + q0 * 8;
  const _Float16* pB1l = WTl + (size_t)r1 * KTOT + q1 * 8;

  const int ps = ((l >> 4) ^ (l & 3)) * 8;
  int offA[4], offB[4];
#pragma unroll
  for (int i = 0; i < 4; ++i) {
    offA[i] = (wr * 64 + i * 16 + (l & 15)) * 32 + ps;
    offB[i] = (wc * 64 + i * 16 + (l & 15)) * 32 + ps;
  }

  f32x4 acc[4][4];
#pragma unroll
  for (int i = 0; i < 4; ++i)
#pragma unroll
    for (int j = 0; j < 4; ++j) acc[i][j] = (f32x4){0.f, 0.f, 0.f, 0.f};

  load_lds16(pA0ch, &ldsAh[0][0] + t0 * 8);
  load_lds16(pA1ch, &ldsAh[0][0] + t1 * 8);
  load_lds16(pA0cl, &ldsAl[0][0] + t0 * 8);
  load_lds16(pA1cl, &ldsAl[0][0] + t1 * 8);
  load_lds16(pB0h, &ldsBh[0][0] + t0 * 8);
  load_lds16(pB1h, &ldsBh[0][0] + t1 * 8);
  load_lds16(pB0l, &ldsBl[0][0] + t0 * 8);
  load_lds16(pB1l, &ldsBl[0][0] + t1 * 8);

  int buf = 0;
  for (int kt = 0; kt < KT; ++kt) {
    __syncthreads();
    if (kt + 1 < KT) {
      int k1 = kt + 1;
      const _Float16* a0 =
          (k1 < KC) ? pA0ch + k1 * 32 : pA0x + (k1 - KC) * 32;
      const _Float16* a1 =
          (k1 < KC) ? pA1ch + k1 * 32 : pA1x + (k1 - KC) * 32;
      load_lds16(a0, &ldsAh[buf ^ 1][0] + t0 * 8);
      load_lds16(a1, &ldsAh[buf ^ 1][0] + t1 * 8);
      if (k1 < KC) {
        load_lds16(pA0cl + k1 * 32, &ldsAl[buf ^ 1][0] + t0 * 8);
        load_lds16(pA1cl + k1 * 32, &ldsAl[buf ^ 1][0] + t1 * 8);
      }
      load_lds16(pB0h + k1 * 32, &ldsBh[buf ^ 1][0] + t0 * 8);
      load_lds16(pB1h + k1 * 32, &ldsBh[buf ^ 1][0] + t1 * 8);
      load_lds16(pB0l + k1 * 32, &ldsBl[buf ^ 1][0] + t0 * 8);
      load_lds16(pB1l + k1 * 32, &ldsBl[buf ^ 1][0] + t1 * 8);
    }
    f16x8 ah[4], bh[4], bl[4];
#pragma unroll
    for (int i = 0; i < 4; ++i) ah[i] = *(const f16x8*)(&ldsAh[buf][offA[i]]);
#pragma unroll
    for (int i = 0; i < 4; ++i) bh[i] = *(const f16x8*)(&ldsBh[buf][offB[i]]);
#pragma unroll
    for (int i = 0; i < 4; ++i) bl[i] = *(const f16x8*)(&ldsBl[buf][offB[i]]);
#pragma unroll
    for (int i = 0; i < 4; ++i)
#pragma unroll
      for (int j = 0; j < 4; ++j) {
        acc[i][j] = __builtin_amdgcn_mfma_f32_16x16x32_f16(ah[i], bh[j],
                                                           acc[i][j], 0, 0, 0);
        acc[i][j] = __builtin_amdgcn_mfma_f32_16x16x32_f16(ah[i], bl[j],
                                                           acc[i][j], 0, 0, 0);
      }
    if (kt < KC) {
      f16x8 al[4];
#pragma unroll
      for (int i = 0; i < 4; ++i)
        al[i] = *(const f16x8*)(&ldsAl[buf][offA[i]]);
#pragma unroll
      for (int i = 0; i < 4; ++i)
#pragma unroll
        for (int j = 0; j < 4; ++j)
          acc[i][j] = __builtin_amdgcn_mfma_f32_16x16x32_f16(al[i], bh[j],
                                                             acc[i][j], 0, 0, 0);
    }
    buf ^= 1;
  }

#pragma unroll
  for (int i = 0; i < 4; ++i) {
    int R = blk * 128 + wr * 64 + i * 16 + (l >> 4) * 4;
#pragma unroll
    for (int j = 0; j < 4; ++j) {
      int o = wc * 64 + j * 16 + (l & 15);
      float bv = bias[o];
#pragma unroll
      for (int rr = 0; rr < 4; ++rr) {
        int Rr = R + rr;
        int n = Rr >> 5, b = Rr & 31;
        size_t base = ((size_t)b * NN + n) * 64;
        float val = 1.f / (1.f + expf(-(acc[i][j][rr] + bv)));
        if (o < 64)
          RHX[base + o] = val * hx[base + o];
        else
          UBUF[base + (o - 64)] = val;
      }
    }
  }
}

// ---------------------------------------------------------------------------
// K6: candidate Wout GEMM (plain fp16 MFMA; terminal op) + tanh + gate -> out.
// ---------------------------------------------------------------------------
__global__ __launch_bounds__(256, 2) void k_wout_c_mfma(
    const _Float16* __restrict__ CAT2h, const _Float16* __restrict__ XP0,
    const _Float16* __restrict__ WTh, const float* __restrict__ bias,
    const float* __restrict__ UBUF, const float* __restrict__ hx,
    float* __restrict__ out) {
  constexpr int KTOT = 192, KC = 4, KT = 6;
  __shared__ _Float16 ldsAh[2][4096];
  __shared__ _Float16 ldsBh[2][2048];
  const int tid = threadIdx.x;
  const int blk = blockIdx.x;
  const int l = tid & 63;
  const int w = tid >> 6;

  const int t0 = tid, t1 = 256 + tid;
  const int r0 = t0 >> 2, q0 = (t0 & 3) ^ (r0 & 3);
  const int r1 = t1 >> 2, q1 = (t1 & 3) ^ (r1 & 3);
  const size_t R0 = (size_t)blk * 128 + r0, R1 = (size_t)blk * 128 + r1;
  const _Float16* pA0ch = CAT2h + R0 * 128 + q0 * 8;
  const _Float16* pA1ch = CAT2h + R1 * 128 + q1 * 8;
  const _Float16* pA0x = XP0 + R0 * 64 + q0 * 8;
  const _Float16* pA1x = XP0 + R1 * 64 + q1 * 8;
  const int rb = tid >> 2, qb = (tid & 3) ^ (rb & 3);
  const _Float16* pBh = WTh + (size_t)rb * KTOT + qb * 8;

  const int ps = ((l >> 4) ^ (l & 3)) * 8;
  int offA[2], offB[4];
#pragma unroll
  for (int i = 0; i < 2; ++i)
    offA[i] = (w * 32 + i * 16 + (l & 15)) * 32 + ps;
#pragma unroll
  for (int j = 0; j < 4; ++j) offB[j] = (j * 16 + (l & 15)) * 32 + ps;

  f32x4 acc[2][4];
#pragma unroll
  for (int i = 0; i < 2; ++i)
#pragma unroll
    for (int j = 0; j < 4; ++j) acc[i][j] = (f32x4){0.f, 0.f, 0.f, 0.f};

  load_lds16(pA0ch, &ldsAh[0][0] + t0 * 8);
  load_lds16(pA1ch, &ldsAh[0][0] + t1 * 8);
  load_lds16(pBh, &ldsBh[0][0] + tid * 8);

  int buf = 0;
  for (int kt = 0; kt < KT; ++kt) {
    __syncthreads();
    if (kt + 1 < KT) {
      int k1 = kt + 1;
      const _Float16* a0 =
          (k1 < KC) ? pA0ch + k1 * 32 : pA0x + (k1 - KC) * 32;
      const _Float16* a1 =
          (k1 < KC) ? pA1ch + k1 * 32 : pA1x + (k1 - KC) * 32;
      load_lds16(a0, &ldsAh[buf ^ 1][0] + t0 * 8);
      load_lds16(a1, &ldsAh[buf ^ 1][0] + t1 * 8);
      load_lds16(pBh + k1 * 32, &ldsBh[buf ^ 1][0] + tid * 8);
    }
    f16x8 ah[2], bh[4];
#pragma unroll
    for (int i = 0; i < 2; ++i) ah[i] = *(const f16x8*)(&ldsAh[buf][offA[i]]);
#pragma unroll
    for (int j = 0; j < 4; ++j) bh[j] = *(const f16x8*)(&ldsBh[buf][offB[j]]);
#pragma unroll
    for (int i = 0; i < 2; ++i)
#pragma unroll
      for (int j = 0; j < 4; ++j)
        acc[i][j] = __builtin_amdgcn_mfma_f32_16x16x32_f16(ah[i], bh[j],
                                                           acc[i][j], 0, 0, 0);
    buf ^= 1;
  }

#pragma unroll
  for (int i = 0; i < 2; ++i) {
    int R = blk * 128 + w * 32 + i * 16 + (l >> 4) * 4;
#pragma unroll
    for (int j = 0; j < 4; ++j) {
      int o = j * 16 + (l & 15);
      float bv = bias[o];
#pragma unroll
      for (int rr = 0; rr < 4; ++rr) {
        int Rr = R + rr;
        int n = Rr >> 5, b = Rr & 31;
        size_t idx = ((size_t)b * NN + n) * 64 + o;
        float cval = tanhf(acc[i][j][rr] + bv);
        float u = UBUF[idx];
        out[idx] = u * hx[idx] + (1.f - u) * cval;
      }
    }
  }
}

// ---------------------------------------------------------------------------
extern "C" void kernel_launch(void* const* d_in, const int* in_sizes, int n_in,
                              void* d_out, int out_size, void* d_ws,
                              size_t ws_size, hipStream_t stream) {
  const float* inputs   = (const float*)d_in[0];
  const float* hx       = (const float*)d_in[1];
  const float* adj      = (const float*)d_in[2];
  const float* mask     = (const float*)d_in[3];
  const float* W_ru     = (const float*)d_in[4];
  const float* Watt_ru  = (const float*)d_in[5];
  const float* Watt1_ru = (const float*)d_in[6];
  const float* Wout_ru  = (const float*)d_in[7];
  const float* b_ru     = (const float*)d_in[8];
  const float* W_c      = (const float*)d_in[9];
  const float* Watt_c   = (const float*)d_in[10];
  const float* Watt1_c  = (const float*)d_in[11];
  const float* Wout_c   = (const float*)d_in[12];
  const float* b_c      = (const float*)d_in[13];

  // workspace arena (~178.5 MB), offsets unchanged
  char* ws = (char*)d_ws;
  _Float16*  XPD   = (_Float16*)(ws + 6291456);
  _Float16*  XP0   = (_Float16*)(ws + 90177536);
  _Float16*  XP0T  = (_Float16*)(ws + 98566144);
  _Float16*  CAT2h = (_Float16*)(ws + 106954752);
  _Float16*  CAT2l = (_Float16*)(ws + 123731968);
  float*     RHX   = (float*)(ws + 140509184);
  float*     UBUF  = (float*)(ws + 148897792);
  _Float16*  A_all = (_Float16*)(ws + 157286400);
  _Float16*  WThru = (_Float16*)(ws + 178257920);
  _Float16*  WTlru = (_Float16*)(ws + 178356224);
  _Float16*  WThc  = (_Float16*)(ws + 178454528);
  _Float16*  WTlc  = (_Float16*)(ws + 178479104);
  float*     out   = (float*)d_out;

  // ---- front: gate proj0 (blocks 0..255) + prep (blocks 256..1519) ----
  k_front<<<1520, 256, 0, stream>>>(inputs, hx, W_ru, XP0, XP0T, adj, mask,
                                    A_all, Wout_ru, Wout_c, WThru, WTlru,
                                    WThc, WTlc);
  // ---- gate gconv (O = 2U = 128) ----
  k_supports2_mfma<4096><<<dim3(32, 80), 256, 0, stream>>>(A_all, XP0T, XPD);
  k_attend_mfma<128><<<1024, 256, 0, stream>>>((const __half*)XPD, Watt_ru,
                                               Watt1_ru, CAT2h, CAT2l);
  k_wout_ru_mfma<<<256, 256, 0, stream>>>(CAT2h, CAT2l, XP0, WThru, WTlru,
                                          b_ru, hx, RHX, UBUF);
  // ---- candidate gconv (O = U = 64), state = r*hx ----
  k_proj0_c<<<128, 256, 0, stream>>>(inputs, RHX, W_c, XP0, XP0T);
  k_supports2_mfma<2048><<<dim3(16, 80), 256, 0, stream>>>(A_all, XP0T, XPD);
  k_attend_mfma<64><<<1024, 256, 0, stream>>>((const __half*)XPD, Watt_c,
                                              Watt1_c, CAT2h, CAT2l);
  k_wout_c_mfma<<<256, 256, 0, stream>>>(CAT2h, XP0, WThc, b_c,
                                         UBUF, hx, out);
}

// Round 13
// 309.365 us; speedup vs baseline: 1.1588x; 1.0103x over previous
//
#include <hip/hip_runtime.h>
#include <hip/hip_fp16.h>
#include <cstdint>
#include <cstddef>

#define NN 1024   // nodes
#define BB 32     // batch

typedef _Float16 f16x8 __attribute__((ext_vector_type(8)));
typedef _Float16 f16x4 __attribute__((ext_vector_type(4)));
typedef float f32x4 __attribute__((ext_vector_type(4)));

__device__ __forceinline__ void load_lds16(const void* g, void* l) {
  __builtin_amdgcn_global_load_lds(
      (const __attribute__((address_space(1))) void*)g,
      (__attribute__((address_space(3))) void*)l, 16, 0, 0);
}

// ---------------------------------------------------------------------------
// prep body: bid<1024 -> build 10 support matrices (fp16);
// bid>=1024 -> transpose+convert Wout matrices to fp16 hi/lo [O][K].
// ---------------------------------------------------------------------------
__device__ __forceinline__ void prep_body(
    int bid, int tid, const float* __restrict__ adj,
    const float* __restrict__ mask, _Float16* __restrict__ A,
    const float* __restrict__ Wru, const float* __restrict__ Wc,
    _Float16* __restrict__ WThru, _Float16* __restrict__ WTlru,
    _Float16* __restrict__ WThc, _Float16* __restrict__ WTlc) {
  if (bid < 1024) {
    int q = bid * 256 + tid;  // 0..262143 quads
    int i = q >> 8;
    int j0 = (q & 255) << 2;
    size_t off = (size_t)i * 1024 + j0;
    float4 a0 = *(const float4*)(adj + off);
    float4 a1 = *(const float4*)(adj + (1u << 20) + off);
    f16x4 r;
    r[0] = a0.x; r[1] = a0.y; r[2] = a0.z; r[3] = a0.w;
    *(f16x4*)(A + off) = r;
    r[0] = a1.x; r[1] = a1.y; r[2] = a1.z; r[3] = a1.w;
    *(f16x4*)(A + (size_t)9 * 1048576 + off) = r;
#pragma unroll
    for (int l = 0; l < 8; ++l) {
      float4 mk = *(const float4*)(mask + (size_t)l * 1048576 + off);
      float4 base = (l < 4) ? a0 : a1;
      r[0] = mk.x * base.x; r[1] = mk.y * base.y;
      r[2] = mk.z * base.z; r[3] = mk.w * base.w;
      *(f16x4*)(A + (size_t)(l + 1) * 1048576 + off) = r;
    }
  } else {
    int id = (bid - 1024) * 256 + tid;
    if (id < 128 * 384) {
      int o = id & 127, k = id >> 7;
      float w = Wru[k * 128 + o];
      _Float16 h = (_Float16)w;
      WThru[o * 384 + k] = h;
      WTlru[o * 384 + k] = (_Float16)(w - (float)h);
    } else {
      int id2 = id - 128 * 384;
      if (id2 < 64 * 192) {
        int o = id2 & 63, k = id2 >> 6;
        float w = Wc[k * 64 + o];
        _Float16 h = (_Float16)w;
        WThc[o * 192 + k] = h;
        WTlc[o * 192 + k] = (_Float16)(w - (float)h);
      }
    }
  }
}

// ---------------------------------------------------------------------------
// proj0 body (fused build+proj GEMM via MFMA).
// XP0[(j*32+b)][o] = sum_f x[b,j,f] * W[f,o]; also XP0T[(b*O+o)][j].
// ---------------------------------------------------------------------------
template <int O>
__device__ __forceinline__ void proj0_body(
    int bx, const float* __restrict__ inp, const float* __restrict__ state,
    const float* __restrict__ W, _Float16* __restrict__ XP0,
    _Float16* __restrict__ XP0T) {
  constexpr int WR = O / 64;      // 2 for O=128, 1 for O=64
  constexpr int WC = 4 / WR;      // 2 or 4
  constexpr int TN = WC * 64;     // 128 or 256
  constexpr int TPR = 256 / TN;   // threads per row: 2 or 1
  __shared__ _Float16 ldsX[TN * 96];  // [row][96 halfs], chunk-swizzled
  const int tid = threadIdx.x;
  const int c0 = bx * TN;  // global (b*1024+j) base, within one b
  const int b = c0 >> 10;
  const int l = tid & 63;
  const int w = tid >> 6;
  const int wr = w / WC, wc = w % WC;

  // A-frags (W^T) in registers, zero-padded f>=66
  f16x8 af[4][3];
#pragma unroll
  for (int i = 0; i < 4; ++i) {
    int o = wr * 64 + i * 16 + (l & 15);
#pragma unroll
    for (int ks = 0; ks < 3; ++ks) {
#pragma unroll
      for (int e = 0; e < 8; ++e) {
        int f = ks * 32 + (l >> 4) * 8 + e;
        af[i][ks][e] = (f < 66) ? (_Float16)W[f * O + o] : (_Float16)0.f;
      }
    }
  }

  // ---- build LDS rows from inputs/state (fp32 -> fp16, chunk-swizzled) ----
  {
    const int row = (TPR == 2) ? (tid >> 1) : tid;
    const int h = (TPR == 2) ? (tid & 1) : 0;
    const int j = (c0 & 1023) + row;
    const float* sp = state + (size_t)b * 65536 + (size_t)j * 64;
    _Float16* ldsRow = ldsX + row * 96;
    const int rsw = row & 3;
    if (TPR == 1 || h == 0) {
      float2 in2 = *(const float2*)(inp + (size_t)b * 2048 + j * 2);
      float sv[48];
#pragma unroll
      for (int u = 0; u < 12; ++u)
        *(f32x4*)(sv + u * 4) = *(const f32x4*)(sp + u * 4);
      f16x8 v;
      v[0] = (_Float16)in2.x;
      v[1] = (_Float16)in2.y;
#pragma unroll
      for (int e = 2; e < 8; ++e) v[e] = (_Float16)sv[e - 2];
      *(f16x8*)(ldsRow + ((0 ^ rsw) << 3)) = v;
#pragma unroll
      for (int c = 1; c < 6; ++c) {
#pragma unroll
        for (int e = 0; e < 8; ++e) v[e] = (_Float16)sv[c * 8 + e - 2];
        int kt = c >> 2, cq = c & 3;
        *(f16x8*)(ldsRow + kt * 32 + ((cq ^ rsw) << 3)) = v;
      }
    }
    if (TPR == 1 || h == 1) {
      float sv2[20];  // s44..s63
#pragma unroll
      for (int u = 0; u < 5; ++u)
        *(f32x4*)(sv2 + u * 4) = *(const f32x4*)(sp + 44 + u * 4);
      f16x8 v;
#pragma unroll
      for (int e = 0; e < 8; ++e) v[e] = (_Float16)sv2[2 + e];  // s46..53
      *(f16x8*)(ldsRow + 32 + ((2 ^ rsw) << 3)) = v;            // c=6
#pragma unroll
      for (int e = 0; e < 8; ++e) v[e] = (_Float16)sv2[10 + e];  // s54..61
      *(f16x8*)(ldsRow + 32 + ((3 ^ rsw) << 3)) = v;             // c=7
      v[0] = (_Float16)sv2[18];
      v[1] = (_Float16)sv2[19];
#pragma unroll
      for (int e = 2; e < 8; ++e) v[e] = (_Float16)0.f;
      *(f16x8*)(ldsRow + 64 + ((0 ^ rsw) << 3)) = v;  // c=8
#pragma unroll
      for (int e = 0; e < 8; ++e) v[e] = (_Float16)0.f;
      *(f16x8*)(ldsRow + 64 + ((1 ^ rsw) << 3)) = v;  // c=9
      *(f16x8*)(ldsRow + 64 + ((2 ^ rsw) << 3)) = v;  // c=10
      *(f16x8*)(ldsRow + 64 + ((3 ^ rsw) << 3)) = v;  // c=11
    }
  }
  __syncthreads();

  const int ps = ((l >> 4) ^ (l & 3)) * 8;
  int offB[4];
#pragma unroll
  for (int j = 0; j < 4; ++j)
    offB[j] = (wc * 64 + j * 16 + (l & 15)) * 96 + ps;

  f32x4 acc[4][4];
#pragma unroll
  for (int i = 0; i < 4; ++i)
#pragma unroll
    for (int j = 0; j < 4; ++j) acc[i][j] = (f32x4){0.f, 0.f, 0.f, 0.f};

#pragma unroll
  for (int kt = 0; kt < 3; ++kt) {
    f16x8 bf[4];
#pragma unroll
    for (int j = 0; j < 4; ++j)
      bf[j] = *(const f16x8*)(&ldsX[offB[j] + kt * 32]);
#pragma unroll
    for (int i = 0; i < 4; ++i)
#pragma unroll
      for (int j = 0; j < 4; ++j)
        acc[i][j] = __builtin_amdgcn_mfma_f32_16x16x32_f16(af[i][kt], bf[j],
                                                           acc[i][j], 0, 0, 0);
  }

#pragma unroll
  for (int i = 0; i < 4; ++i) {
    int ob = wr * 64 + i * 16 + (l >> 4) * 4;  // 4 consecutive o
#pragma unroll
    for (int j = 0; j < 4; ++j) {
      int jn = (c0 & 1023) + wc * 64 + j * 16 + (l & 15);
      f16x4 hv;
#pragma unroll
      for (int r = 0; r < 4; ++r) {
        hv[r] = (_Float16)acc[i][j][r];
        XP0T[((size_t)b * O + ob + r) * 1024 + jn] = hv[r];
      }
      *(f16x4*)(XP0 + ((size_t)jn * 32 + b) * O + ob) = hv;
    }
  }
}

// ---------------------------------------------------------------------------
// K_front: blocks 0..255 = proj0<128> (gate); blocks 256..1519 = prep.
// ---------------------------------------------------------------------------
__global__ __launch_bounds__(256, 2) void k_front(
    const float* __restrict__ inputs, const float* __restrict__ hx,
    const float* __restrict__ W_ru, _Float16* __restrict__ XP0,
    _Float16* __restrict__ XP0T, const float* __restrict__ adj,
    const float* __restrict__ mask, _Float16* __restrict__ A,
    const float* __restrict__ Wru, const float* __restrict__ Wc,
    _Float16* __restrict__ WThru, _Float16* __restrict__ WTlru,
    _Float16* __restrict__ WThc, _Float16* __restrict__ WTlc) {
  if (blockIdx.x < 256) {
    proj0_body<128>(blockIdx.x, inputs, hx, W_ru, XP0, XP0T);
  } else {
    prep_body(blockIdx.x - 256, threadIdx.x, adj, mask, A, Wru, Wc, WThru,
              WTlru, WThc, WTlc);
  }
}

// ---------------------------------------------------------------------------
// K2b: candidate proj0 (standalone; depends on RHX).
// ---------------------------------------------------------------------------
__global__ __launch_bounds__(256, 2) void k_proj0_c(
    const float* __restrict__ inp, const float* __restrict__ state,
    const float* __restrict__ W, _Float16* __restrict__ XP0,
    _Float16* __restrict__ XP0T) {
  proj0_body<64>(blockIdx.x, inp, state, W, XP0, XP0T);
}

// ---------------------------------------------------------------------------
// K3: supports GEMM, ring-3 counted-vmcnt pipeline (T4 at CONSTANT occupancy:
// 3 slots x 16KB = 48KB LDS -> still 3 blocks/CU, unlike round-9's 72KB ring).
// Same 128x128 tile, BK=32, 16x16x32 MFMA, 4 waves 2x2, same swizzle.
// Per iter t: vmcnt(4) [tile t landed, t+1 in flight] -> s_barrier ->
// stage t+2 into slot (t+2)%3 -> ds_read/MFMA tile t.  Loads get 2 compute
// iterations of latency budget; never drained to 0 until the last step.
// + coalesced epilogue via swizzled LDS transpose (round-11 proven).
// ---------------------------------------------------------------------------
template <int CN>
__global__ __launch_bounds__(256, 2) void k_supports2_mfma(
    const _Float16* __restrict__ A, const _Float16* __restrict__ BT,
    _Float16* __restrict__ XPD) {
  __shared__ _Float16 ldsU[6][4096];  // [0..2]=A ring, [3..5]=B ring (48KB)
  const int tid = threadIdx.x;
  const int bn = blockIdx.x;  // col tiles (CN/128)
  const int bm = blockIdx.y;  // 0..79
  const int l = tid & 63;
  const int w = tid >> 6;
  const int wr = w >> 1, wc = w & 1;

  const int t0 = tid, t1 = 256 + tid;
  const int r0 = t0 >> 2, q0 = (t0 & 3) ^ (r0 & 3);
  const int r1 = t1 >> 2, q1 = (t1 & 3) ^ (r1 & 3);
  const _Float16* gA0 = A + ((size_t)(bm * 128 + r0)) * 1024 + q0 * 8;
  const _Float16* gA1 = A + ((size_t)(bm * 128 + r1)) * 1024 + q1 * 8;
  const _Float16* gB0 = BT + ((size_t)(bn * 128 + r0)) * 1024 + q0 * 8;
  const _Float16* gB1 = BT + ((size_t)(bn * 128 + r1)) * 1024 + q1 * 8;

#define STAGE_R3(t, s)                                   \
  {                                                      \
    int k0_ = (t) * 32;                                  \
    load_lds16(gA0 + k0_, &ldsU[(s)][0] + t0 * 8);       \
    load_lds16(gA1 + k0_, &ldsU[(s)][0] + t1 * 8);       \
    load_lds16(gB0 + k0_, &ldsU[3 + (s)][0] + t0 * 8);   \
    load_lds16(gB1 + k0_, &ldsU[3 + (s)][0] + t1 * 8);   \
  }

  const int ps = ((l >> 4) ^ (l & 3)) * 8;
  int offA[4], offB[4];
#pragma unroll
  for (int i = 0; i < 4; ++i) {
    offA[i] = (wr * 64 + i * 16 + (l & 15)) * 32 + ps;
    offB[i] = (wc * 64 + i * 16 + (l & 15)) * 32 + ps;
  }

  f32x4 acc[4][4];
#pragma unroll
  for (int i = 0; i < 4; ++i)
#pragma unroll
    for (int j = 0; j < 4; ++j) acc[i][j] = (f32x4){0.f, 0.f, 0.f, 0.f};

  // prologue: stage tiles 0,1 into slots 0,1
  STAGE_R3(0, 0);
  STAGE_R3(1, 1);

  int slot = 0;
  for (int kt = 0; kt < 32; ++kt) {
    if (kt < 31)
      asm volatile("s_waitcnt vmcnt(4)" ::: "memory");
    else
      asm volatile("s_waitcnt vmcnt(0)" ::: "memory");
    __builtin_amdgcn_sched_barrier(0);
    __builtin_amdgcn_s_barrier();
    __builtin_amdgcn_sched_barrier(0);
    const int s2 = (slot >= 1) ? slot - 1 : 2;  // (kt+2)%3
    if (kt + 2 < 32) STAGE_R3(kt + 2, s2);
    f16x8 af[4], bf[4];
#pragma unroll
    for (int i = 0; i < 4; ++i)
      af[i] = *(const f16x8*)(&ldsU[slot][offA[i]]);
#pragma unroll
    for (int i = 0; i < 4; ++i)
      bf[i] = *(const f16x8*)(&ldsU[3 + slot][offB[i]]);
#pragma unroll
    for (int i = 0; i < 4; ++i)
#pragma unroll
      for (int j = 0; j < 4; ++j)
        acc[i][j] = __builtin_amdgcn_mfma_f32_16x16x32_f16(af[i], bf[j],
                                                           acc[i][j], 0, 0, 0);
    slot = (slot == 2) ? 0 : slot + 1;
  }
#undef STAGE_R3

  // ---- coalesced epilogue via swizzled LDS transpose ----
  __syncthreads();  // all ds_reads of the K-loop complete; no loads in flight
  {
    _Float16* C = &ldsU[0][0];  // 128x128 fp16 = 32KB (spans slots 0..3)
#pragma unroll
    for (int i = 0; i < 4; ++i) {
      int Rl = wr * 64 + i * 16 + (l >> 4) * 4;
#pragma unroll
      for (int j = 0; j < 4; ++j) {
        int Cc = wc * 64 + j * 16 + (l & 15);
#pragma unroll
        for (int r = 0; r < 4; ++r) {
          int row = Rl + r;
          C[row * 128 + (((Cc >> 3) ^ (row & 7)) << 3) + (Cc & 7)] =
              (_Float16)acc[i][j][r];
        }
      }
    }
    __syncthreads();
#pragma unroll
    for (int it = 0; it < 8; ++it) {
      int flat = it * 256 + tid;
      int row = flat >> 4;
      int c2 = flat & 15;
      f16x8 v = *(const f16x8*)(&C[row * 128 + ((c2 ^ (row & 7)) << 3)]);
      *(f16x8*)(XPD + (size_t)(bm * 128 + row) * CN + bn * 128 + c2 * 8) = v;
    }
  }
}

// ---------------------------------------------------------------------------
// K4: attention via MFMA (unchanged).
// ---------------------------------------------------------------------------
template <int O>
__global__ __launch_bounds__(256) void k_attend_mfma(
    const __half* __restrict__ XPD, const float* __restrict__ Watt,
    const float* __restrict__ Watt1, _Float16* __restrict__ CAT2h,
    _Float16* __restrict__ CAT2l) {
  constexpr int MTW = O / 64;       // q-tiles per wave (2 or 1)
  constexpr int KS = O / 32;        // k-steps (4 or 2)
  constexpr int SLOTS = O / 8;      // 16B slots per row (16 or 8)
  constexpr int SWZ = SLOTS - 1;
  const int n = blockIdx.x;
  const int tid = threadIdx.x;
  const int l = tid & 63;
  const int w = tid >> 6;

  __shared__ _Float16 xpL[160 * O];
  __shared__ float sPartL[4][160];
  __shared__ float aL[32][5];

  const int qbase = w * (O / 4);
  f16x8 afr[MTW][KS];
#pragma unroll
  for (int mt = 0; mt < MTW; ++mt) {
    const int q = qbase + mt * 16 + (l & 15);
#pragma unroll
    for (int ks = 0; ks < KS; ++ks) {
#pragma unroll
      for (int e = 0; e < 8; ++e) {
        int o = ks * 32 + (l >> 4) * 8 + e;
        afr[mt][ks][e] = (_Float16)Watt[((size_t)n * O + o) * O + q];
      }
    }
  }
  float wt1[MTW][4];
#pragma unroll
  for (int mt = 0; mt < MTW; ++mt)
#pragma unroll
    for (int r = 0; r < 4; ++r)
      wt1[mt][r] = Watt1[(size_t)n * O + qbase + mt * 16 + (l >> 4) * 4 + r];

  for (int g = 0; g < 2; ++g) {
    if (g) __syncthreads();
    {
      const f16x8* xsrc = reinterpret_cast<const f16x8*>(XPD);
      f16x8* xdst = reinterpret_cast<f16x8*>(xpL);
      for (int p = tid; p < 160 * SLOTS; p += 256) {
        int row = p / SLOTS;
        int sc = p - row * SLOTS;
        int phys = sc ^ (row & SWZ);
        int si = row >> 5, b = row & 31;
        size_t gi = ((size_t)(g * 5 + si) * 1024 + n) * (size_t)(4 * O) +
                    b * (O / 8) + sc;
        xdst[row * SLOTS + phys] = xsrc[gi];
      }
    }
    __syncthreads();

    for (int nt = 0; nt < 10; ++nt) {
      f32x4 acc[MTW];
#pragma unroll
      for (int mt = 0; mt < MTW; ++mt) acc[mt] = (f32x4){0.f, 0.f, 0.f, 0.f};
      const int row = nt * 16 + (l & 15);
#pragma unroll
      for (int ks = 0; ks < KS; ++ks) {
        int phys = (ks * 4 + (l >> 4)) ^ (row & SWZ);
        f16x8 bf = *(const f16x8*)(&xpL[row * O + phys * 8]);
#pragma unroll
        for (int mt = 0; mt < MTW; ++mt)
          acc[mt] = __builtin_amdgcn_mfma_f32_16x16x32_f16(afr[mt][ks], bf,
                                                           acc[mt], 0, 0, 0);
      }
      float sp = 0.f;
#pragma unroll
      for (int mt = 0; mt < MTW; ++mt)
#pragma unroll
        for (int r = 0; r < 4; ++r)
          sp += fmaxf(acc[mt][r], 0.f) * wt1[mt][r];
      sp += __shfl_xor(sp, 16);
      sp += __shfl_xor(sp, 32);
      if (l < 16) sPartL[w][nt * 16 + l] = sp;
    }
    __syncthreads();

    if (tid < 32) {
      const int b = tid;
      float sv[5];
#pragma unroll
      for (int k = 0; k < 5; ++k) {
        int row = k * 32 + b;
        sv[k] = sPartL[0][row] + sPartL[1][row] + sPartL[2][row] +
                sPartL[3][row];
      }
      float mx = sv[0];
#pragma unroll
      for (int k = 1; k < 5; ++k) mx = fmaxf(mx, sv[k]);
      float e[5], sum = 0.f;
#pragma unroll
      for (int k = 0; k < 5; ++k) {
        e[k] = expf(sv[k] - mx);
        sum += e[k];
      }
      float inv = 1.f / sum;
#pragma unroll
      for (int k = 0; k < 5; ++k) aL[b][k] = e[k] * inv;
    }
    __syncthreads();

    for (int it = 0; it < SLOTS * 32 / 256; ++it) {
      int idx = it * 256 + tid;
      int b = idx & 31;
      int sc = idx >> 5;
      float o8[8] = {0.f, 0.f, 0.f, 0.f, 0.f, 0.f, 0.f, 0.f};
#pragma unroll
      for (int si = 0; si < 5; ++si) {
        int row = si * 32 + b;
        int phys = sc ^ (row & SWZ);
        f16x8 xv = *(const f16x8*)(&xpL[row * O + phys * 8]);
        float a = aL[b][si];
#pragma unroll
        for (int j = 0; j < 8; ++j) o8[j] += a * (float)xv[j];
      }
      f16x8 hv, lv;
#pragma unroll
      for (int j = 0; j < 8; ++j) {
        hv[j] = (_Float16)o8[j];
        lv[j] = (_Float16)(o8[j] - (float)hv[j]);
      }
      size_t doff = ((size_t)n * 32 + b) * (2 * O) + g * O + sc * 8;
      *reinterpret_cast<f16x8*>(CAT2h + doff) = hv;
      *reinterpret_cast<f16x8*>(CAT2l + doff) = lv;
    }
  }
}

// ---------------------------------------------------------------------------
// K5: ru Wout GEMM via split-fp16 MFMA + fused sigmoid (unchanged).
// ---------------------------------------------------------------------------
__global__ __launch_bounds__(256, 2) void k_wout_ru_mfma(
    const _Float16* __restrict__ CAT2h, const _Float16* __restrict__ CAT2l,
    const _Float16* __restrict__ XP0, const _Float16* __restrict__ WTh,
    const _Float16* __restrict__ WTl, const float* __restrict__ bias,
    const float* __restrict__ hx, float* __restrict__ RHX,
    float* __restrict__ UBUF) {
  constexpr int KTOT = 384, KC = 8, KT = 12;
  __shared__ _Float16 ldsAh[2][4096];
  __shared__ _Float16 ldsAl[2][4096];
  __shared__ _Float16 ldsBh[2][4096];
  __shared__ _Float16 ldsBl[2][4096];
  const int tid = threadIdx.x;
  const int blk = blockIdx.x;
  const int l = tid & 63;
  const int w = tid >> 6;
  const int wr = w >> 1, wc = w & 1;

  const int t0 = tid, t1 = 256 + tid;
  const int r0 = t0 >> 2, q0 = (t0 & 3) ^ (r0 & 3);
  const int r1 = t1 >> 2, q1 = (t1 & 3) ^ (r1 & 3);
  const size_t R0 = (size_t)blk * 128 + r0, R1 = (size_t)blk * 128 + r1;
  const _Float16* pA0ch = CAT2h + R0 * 256 + q0 * 8;
  const _Float16* pA1ch = CAT2h + R1 * 256 + q1 * 8;
  const _Float16* pA0cl = CAT2l + R0 * 256 + q0 * 8;
  const _Float16* pA1cl = CAT2l + R1 * 256 + q1 * 8;
  const _Float16* pA0x = XP0 + R0 * 128 + q0 * 8;
  const _Float16* pA1x = XP0 + R1 * 128 + q1 * 8;
  const _Float16* pB0h = WTh + (size_t)r0 * KTOT + q0 * 8;
  const _Float16* pB1h = WTh + (size_t)r1 * KTOT + q1 * 8;
  const _Float16* pB0l = WTl + (size_t)r0 * KTOT + q0 * 8;
  const _Float16* pB1l = WTl + (size_t)r1 * KTOT + q1 * 8;

  const int ps = ((l >> 4) ^ (l & 3)) * 8;
  int offA[4], offB[4];
#pragma unroll
  for (int i = 0; i < 4; ++i) {
    offA[i] = (wr * 64 + i * 16 + (l & 15)) * 32 + ps;
    offB[i] = (wc * 64 + i * 16 + (l & 15)) * 32 + ps;
  }

  f32x4 acc[4][4];
#pragma unroll
  for (int i = 0; i < 4; ++i)
#pragma unroll
    for (int j = 0; j < 4; ++j) acc[i][j] = (f32x4){0.f, 0.f, 0.f, 0.f};

  load_lds16(pA0ch, &ldsAh[0][0] + t0 * 8);
  load_lds16(pA1ch, &ldsAh[0][0] + t1 * 8);
  load_lds16(pA0cl, &ldsAl[0][0] + t0 * 8);
  load_lds16(pA1cl, &ldsAl[0][0] + t1 * 8);
  load_lds16(pB0h, &ldsBh[0][0] + t0 * 8);
  load_lds16(pB1h, &ldsBh[0][0] + t1 * 8);
  load_lds16(pB0l, &ldsBl[0][0] + t0 * 8);
  load_lds16(pB1l, &ldsBl[0][0] + t1 * 8);

  int buf = 0;
  for (int kt = 0; kt < KT; ++kt) {
    __syncthreads();
    if (kt + 1 < KT) {
      int k1 = kt + 1;
      const _Float16* a0 =
          (k1 < KC) ? pA0ch + k1 * 32 : pA0x + (k1 - KC) * 32;
      const _Float16* a1 =
          (k1 < KC) ? pA1ch + k1 * 32 : pA1x + (k1 - KC) * 32;
      load_lds16(a0, &ldsAh[buf ^ 1][0] + t0 * 8);
      load_lds16(a1, &ldsAh[buf ^ 1][0] + t1 * 8);
      if (k1 < KC) {
        load_lds16(pA0cl + k1 * 32, &ldsAl[buf ^ 1][0] + t0 * 8);
        load_lds16(pA1cl + k1 * 32, &ldsAl[buf ^ 1][0] + t1 * 8);
      }
      load_lds16(pB0h + k1 * 32, &ldsBh[buf ^ 1][0] + t0 * 8);
      load_lds16(pB1h + k1 * 32, &ldsBh[buf ^ 1][0] + t1 * 8);
      load_lds16(pB0l + k1 * 32, &ldsBl[buf ^ 1][0] + t0 * 8);
      load_lds16(pB1l + k1 * 32, &ldsBl[buf ^ 1][0] + t1 * 8);
    }
    f16x8 ah[4], bh[4], bl[4];
#pragma unroll
    for (int i = 0; i < 4; ++i) ah[i] = *(const f16x8*)(&ldsAh[buf][offA[i]]);
#pragma unroll
    for (int i = 0; i < 4; ++i) bh[i] = *(const f16x8*)(&ldsBh[buf][offB[i]]);
#pragma unroll
    for (int i = 0; i < 4; ++i) bl[i] = *(const f16x8*)(&ldsBl[buf][offB[i]]);
#pragma unroll
    for (int i = 0; i < 4; ++i)
#pragma unroll
      for (int j = 0; j < 4; ++j) {
        acc[i][j] = __builtin_amdgcn_mfma_f32_16x16x32_f16(ah[i], bh[j],
                                                           acc[i][j], 0, 0, 0);
        acc[i][j] = __builtin_amdgcn_mfma_f32_16x16x32_f16(ah[i], bl[j],
                                                           acc[i][j], 0, 0, 0);
      }
    if (kt < KC) {
      f16x8 al[4];
#pragma unroll
      for (int i = 0; i < 4; ++i)
        al[i] = *(const f16x8*)(&ldsAl[buf][offA[i]]);
#pragma unroll
      for (int i = 0; i < 4; ++i)
#pragma unroll
        for (int j = 0; j < 4; ++j)
          acc[i][j] = __builtin_amdgcn_mfma_f32_16x16x32_f16(al[i], bh[j],
                                                             acc[i][j], 0, 0, 0);
    }
    buf ^= 1;
  }

#pragma unroll
  for (int i = 0; i < 4; ++i) {
    int R = blk * 128 + wr * 64 + i * 16 + (l >> 4) * 4;
#pragma unroll
    for (int j = 0; j < 4; ++j) {
      int o = wc * 64 + j * 16 + (l & 15);
      float bv = bias[o];
#pragma unroll
      for (int rr = 0; rr < 4; ++rr) {
        int Rr = R + rr;
        int n = Rr >> 5, b = Rr & 31;
        size_t base = ((size_t)b * NN + n) * 64;
        float val = 1.f / (1.f + expf(-(acc[i][j][rr] + bv)));
        if (o < 64)
          RHX[base + o] = val * hx[base + o];
        else
          UBUF[base + (o - 64)] = val;
      }
    }
  }
}

// ---------------------------------------------------------------------------
// K6: candidate Wout GEMM (plain fp16 MFMA; terminal op) + tanh + gate -> out.
// ---------------------------------------------------------------------------
__global__ __launch_bounds__(256, 2) void k_wout_c_mfma(
    const _Float16* __restrict__ CAT2h, const _Float16* __restrict__ XP0,
    const _Float16* __restrict__ WTh, const float* __restrict__ bias,
    const float* __restrict__ UBUF, const float* __restrict__ hx,
    float* __restrict__ out) {
  constexpr int KTOT = 192, KC = 4, KT = 6;
  __shared__ _Float16 ldsAh[2][4096];
  __shared__ _Float16 ldsBh[2][2048];
  const int tid = threadIdx.x;
  const int blk = blockIdx.x;
  const int l = tid & 63;
  const int w = tid >> 6;

  const int t0 = tid, t1 = 256 + tid;
  const int r0 = t0 >> 2, q0 = (t0 & 3) ^ (r0 & 3);
  const int r1 = t1 >> 2, q1 = (t1 & 3) ^ (r1 & 3);
  const size_t R0 = (size_t)blk * 128 + r0, R1 = (size_t)blk * 128 + r1;
  const _Float16* pA0ch = CAT2h + R0 * 128 + q0 * 8;
  const _Float16* pA1ch = CAT2h + R1 * 128 + q1 * 8;
  const _Float16* pA0x = XP0 + R0 * 64 + q0 * 8;
  const _Float16* pA1x = XP0 + R1 * 64 + q1 * 8;
  const int rb = tid >> 2, qb = (tid & 3) ^ (rb & 3);
  const _Float16* pBh = WTh + (size_t)rb * KTOT + qb * 8;

  const int ps = ((l >> 4) ^ (l & 3)) * 8;
  int offA[2], offB[4];
#pragma unroll
  for (int i = 0; i < 2; ++i)
    offA[i] = (w * 32 + i * 16 + (l & 15)) * 32 + ps;
#pragma unroll
  for (int j = 0; j < 4; ++j) offB[j] = (j * 16 + (l & 15)) * 32 + ps;

  f32x4 acc[2][4];
#pragma unroll
  for (int i = 0; i < 2; ++i)
#pragma unroll
    for (int j = 0; j < 4; ++j) acc[i][j] = (f32x4){0.f, 0.f, 0.f, 0.f};

  load_lds16(pA0ch, &ldsAh[0][0] + t0 * 8);
  load_lds16(pA1ch, &ldsAh[0][0] + t1 * 8);
  load_lds16(pBh, &ldsBh[0][0] + tid * 8);

  int buf = 0;
  for (int kt = 0; kt < KT; ++kt) {
    __syncthreads();
    if (kt + 1 < KT) {
      int k1 = kt + 1;
      const _Float16* a0 =
          (k1 < KC) ? pA0ch + k1 * 32 : pA0x + (k1 - KC) * 32;
      const _Float16* a1 =
          (k1 < KC) ? pA1ch + k1 * 32 : pA1x + (k1 - KC) * 32;
      load_lds16(a0, &ldsAh[buf ^ 1][0] + t0 * 8);
      load_lds16(a1, &ldsAh[buf ^ 1][0] + t1 * 8);
      load_lds16(pBh + k1 * 32, &ldsBh[buf ^ 1][0] + tid * 8);
    }
    f16x8 ah[2], bh[4];
#pragma unroll
    for (int i = 0; i < 2; ++i) ah[i] = *(const f16x8*)(&ldsAh[buf][offA[i]]);
#pragma unroll
    for (int j = 0; j < 4; ++j) bh[j] = *(const f16x8*)(&ldsBh[buf][offB[j]]);
#pragma unroll
    for (int i = 0; i < 2; ++i)
#pragma unroll
      for (int j = 0; j < 4; ++j)
        acc[i][j] = __builtin_amdgcn_mfma_f32_16x16x32_f16(ah[i], bh[j],
                                                           acc[i][j], 0, 0, 0);
    buf ^= 1;
  }

#pragma unroll
  for (int i = 0; i < 2; ++i) {
    int R = blk * 128 + w * 32 + i * 16 + (l >> 4) * 4;
#pragma unroll
    for (int j = 0; j < 4; ++j) {
      int o = j * 16 + (l & 15);
      float bv = bias[o];
#pragma unroll
      for (int rr = 0; rr < 4; ++rr) {
        int Rr = R + rr;
        int n = Rr >> 5, b = Rr & 31;
        size_t idx = ((size_t)b * NN + n) * 64 + o;
        float cval = tanhf(acc[i][j][rr] + bv);
        float u = UBUF[idx];
        out[idx] = u * hx[idx] + (1.f - u) * cval;
      }
    }
  }
}

// ---------------------------------------------------------------------------
extern "C" void kernel_launch(void* const* d_in, const int* in_sizes, int n_in,
                              void* d_out, int out_size, void* d_ws,
                              size_t ws_size, hipStream_t stream) {
  const float* inputs   = (const float*)d_in[0];
  const float* hx       = (const float*)d_in[1];
  const float* adj      = (const float*)d_in[2];
  const float* mask     = (const float*)d_in[3];
  const float* W_ru     = (const float*)d_in[4];
  const float* Watt_ru  = (const float*)d_in[5];
  const float* Watt1_ru = (const float*)d_in[6];
  const float* Wout_ru  = (const float*)d_in[7];
  const float* b_ru     = (const float*)d_in[8];
  const float* W_c      = (const float*)d_in[9];
  const float* Watt_c   = (const float*)d_in[10];
  const float* Watt1_c  = (const float*)d_in[11];
  const float* Wout_c   = (const float*)d_in[12];
  const float* b_c      = (const float*)d_in[13];

  // workspace arena (~178.5 MB), offsets unchanged
  char* ws = (char*)d_ws;
  _Float16*  XPD   = (_Float16*)(ws + 6291456);
  _Float16*  XP0   = (_Float16*)(ws + 90177536);
  _Float16*  XP0T  = (_Float16*)(ws + 98566144);
  _Float16*  CAT2h = (_Float16*)(ws + 106954752);
  _Float16*  CAT2l = (_Float16*)(ws + 123731968);
  float*     RHX   = (float*)(ws + 140509184);
  float*     UBUF  = (float*)(ws + 148897792);
  _Float16*  A_all = (_Float16*)(ws + 157286400);
  _Float16*  WThru = (_Float16*)(ws + 178257920);
  _Float16*  WTlru = (_Float16*)(ws + 178356224);
  _Float16*  WThc  = (_Float16*)(ws + 178454528);
  _Float16*  WTlc  = (_Float16*)(ws + 178479104);
  float*     out   = (float*)d_out;

  // ---- front: gate proj0 (blocks 0..255) + prep (blocks 256..1519) ----
  k_front<<<1520, 256, 0, stream>>>(inputs, hx, W_ru, XP0, XP0T, adj, mask,
                                    A_all, Wout_ru, Wout_c, WThru, WTlru,
                                    WThc, WTlc);
  // ---- gate gconv (O = 2U = 128) ----
  k_supports2_mfma<4096><<<dim3(32, 80), 256, 0, stream>>>(A_all, XP0T, XPD);
  k_attend_mfma<128><<<1024, 256, 0, stream>>>((const __half*)XPD, Watt_ru,
                                               Watt1_ru, CAT2h, CAT2l);
  k_wout_ru_mfma<<<256, 256, 0, stream>>>(CAT2h, CAT2l, XP0, WThru, WTlru,
                                          b_ru, hx, RHX, UBUF);
  // ---- candidate gconv (O = U = 64), state = r*hx ----
  k_proj0_c<<<128, 256, 0, stream>>>(inputs, RHX, W_c, XP0, XP0T);
  k_supports2_mfma<2048><<<dim3(16, 80), 256, 0, stream>>>(A_all, XP0T, XPD);
  k_attend_mfma<64><<<1024, 256, 0, stream>>>((const __half*)XPD, Watt_c,
                                              Watt1_c, CAT2h, CAT2l);
  k_wout_c_mfma<<<256, 256, 0, stream>>>(CAT2h, XP0, WThc, b_c,
                                         UBUF, hx, out);
}